// Round 3
// baseline (212.469 us; speedup 1.0000x reference)
//
#include <hip/hip_runtime.h>
#include <hip/hip_bf16.h>
#include <stdint.h>

typedef __attribute__((ext_vector_type(4))) float          f32x4;
typedef __attribute__((ext_vector_type(4))) float          f4;
typedef __attribute__((ext_vector_type(2))) unsigned int   u32x2;
typedef __bf16 bf16_t;
typedef __attribute__((ext_vector_type(8))) bf16_t         bf16x8;
typedef __attribute__((ext_vector_type(8))) unsigned short u16x8;
typedef __attribute__((ext_vector_type(4))) unsigned short u16x4;

#define NB 2
#define NS 4096
#define ND 768
#define NH 12
#define NW 256

__device__ __forceinline__ unsigned short f2bf(float f) {
  union { float f; unsigned u; } v; v.f = f;
  unsigned r = v.u + 0x7fffu + ((v.u >> 16) & 1u);
  return (unsigned short)(r >> 16);
}

__device__ __forceinline__ void gload16(const void* g, void* l) {
  __builtin_amdgcn_global_load_lds((const __attribute__((address_space(1))) void*)g,
                                   (__attribute__((address_space(3))) void*)l, 16, 0, 0);
}

// ---------------- f32 -> bf16 casts ----------------
__global__ void cast_kernel(const float* __restrict__ in, unsigned short* __restrict__ out, int n4) {
  int i = blockIdx.x * blockDim.x + threadIdx.x;
  int stride = gridDim.x * blockDim.x;
  for (; i < n4; i += stride) {
    f4 v = reinterpret_cast<const f4*>(in)[i];
    unsigned u0 = (unsigned)f2bf(v.x) | ((unsigned)f2bf(v.y) << 16);
    unsigned u1 = (unsigned)f2bf(v.z) | ((unsigned)f2bf(v.w) << 16);
    u32x2 o = {u0, u1};
    reinterpret_cast<u32x2*>(out)[i] = o;
  }
}

// all three weight matrices in one launch (each 768*768, n4 = 147456 float4-groups)
__global__ void cast3_kernel(const float* __restrict__ w0, const float* __restrict__ w1,
                             const float* __restrict__ w2, unsigned short* __restrict__ o0,
                             unsigned short* __restrict__ o1, unsigned short* __restrict__ o2) {
  const int n4 = 768 * 768 / 4;
  int i = blockIdx.x * blockDim.x + threadIdx.x;
  int stride = gridDim.x * blockDim.x;
  for (; i < 3 * n4; i += stride) {
    int m = i / n4, j = i - m * n4;
    const float* in = (m == 0) ? w0 : ((m == 1) ? w1 : w2);
    unsigned short* out = (m == 0) ? o0 : ((m == 1) ? o1 : o2);
    f4 v = reinterpret_cast<const f4*>(in)[j];
    unsigned u0 = (unsigned)f2bf(v.x) | ((unsigned)f2bf(v.y) << 16);
    unsigned u1 = (unsigned)f2bf(v.z) | ((unsigned)f2bf(v.w) << 16);
    u32x2 o = {u0, u1};
    reinterpret_cast<u32x2*>(out)[j] = o;
  }
}

// ---------------- fused QKV projection GEMM ----------------
// C[i,j] = sum_k A[i,k] * W[j,k]   (A: 8192x768 bf16, W rows: 768x768 bf16)
__global__ __launch_bounds__(256) void qkv_gemm(
    const unsigned short* __restrict__ Ab,
    const unsigned short* __restrict__ Wqb,
    const unsigned short* __restrict__ Wkb,
    const unsigned short* __restrict__ Wvb,
    const float* __restrict__ bqp, const float* __restrict__ bkp, const float* __restrict__ bvp,
    unsigned short* __restrict__ Qw, unsigned short* __restrict__ Kw, unsigned short* __restrict__ Vw) {
  __shared__ unsigned short As[128 * 32];
  __shared__ unsigned short Bs[128 * 32];

  // XCD-aware swizzle: 1152 blocks = 8 XCDs x 144. Each XCD: 8 bm-panels x 18 bn
  // -> A-panel re-reads (18 blocks share a panel) become L2 hits.
  int phys = blockIdx.x;
  int logical = (phys & 7) * 144 + (phys >> 3);
  int bn = logical % 18, bm = logical / 18;
  int mat = bn / 6, bnn = bn % 6;
  const unsigned short* Wm = (mat == 0) ? Wqb : ((mat == 1) ? Wkb : Wvb);
  const float* bias = (mat == 0) ? bqp : ((mat == 1) ? bkp : bvp);
  unsigned short* dst = (mat == 0) ? Qw : ((mat == 1) ? Kw : Vw);

  int t = threadIdx.x;
  int w = t >> 6, l = t & 63;
  int lg = l >> 4, ln = l & 15;
  int wm = w & 1, wn = w >> 1;

  f32x4 acc[4][4];
#pragma unroll
  for (int i = 0; i < 4; i++)
#pragma unroll
    for (int j = 0; j < 4; j++) acc[i][j] = f32x4{0.f, 0.f, 0.f, 0.f};

  for (int kt = 0; kt < 24; ++kt) {
    __syncthreads();
#pragma unroll
    for (int is = 0; is < 2; ++is) {
      int chunk = is * 256 + t;       // 0..511, 16B each
      int row = chunk >> 2;           // 0..127
      int c8 = (chunk & 3) * 8;       // elem offset in 32-wide k-slice
      gload16(Ab + ((size_t)(bm * 128 + row)) * 768 + kt * 32 + c8, As + chunk * 8);
      gload16(Wm + ((size_t)(bnn * 128 + row)) * 768 + kt * 32 + c8, Bs + chunk * 8);
    }
    __syncthreads();
    bf16x8 af[4], bfr[4];
#pragma unroll
    for (int i = 0; i < 4; i++) {
      af[i]  = *reinterpret_cast<const bf16x8*>(As + (wm * 64 + i * 16 + ln) * 32 + lg * 8);
      bfr[i] = *reinterpret_cast<const bf16x8*>(Bs + (wn * 64 + i * 16 + ln) * 32 + lg * 8);
    }
#pragma unroll
    for (int i = 0; i < 4; i++)
#pragma unroll
      for (int j = 0; j < 4; j++)
        acc[i][j] = __builtin_amdgcn_mfma_f32_16x16x32_bf16(af[i], bfr[j], acc[i][j], 0, 0, 0);
  }

  // epilogue: bias (+ 1/8 scale for Q), convert, scatter to (B,H,S,64)
#pragma unroll
  for (int j = 0; j < 4; j++) {
    int col = bnn * 128 + wn * 64 + j * 16 + ln;  // within-matrix column 0..767
    float bv_ = bias[col];
    int hh = col >> 6, dd = col & 63;
#pragma unroll
    for (int i = 0; i < 4; i++) {
#pragma unroll
      for (int r = 0; r < 4; r++) {
        int tok = bm * 128 + wm * 64 + i * 16 + lg * 4 + r;
        int bb = tok >> 12, ss = tok & 4095;
        float v = acc[i][j][r] + bv_;
        if (mat == 0) v *= 0.125f;
        dst[(((size_t)bb * 12 + hh) * 4096 + ss) * 64 + dd] = f2bf(v);
      }
    }
  }
}

// ---------------- fused band + global attention ----------------
// 1 block = (b,h, 128-query chunk). 8 waves x 16 query rows each.
__global__ __launch_bounds__(512) void attn_kernel(
    const unsigned short* __restrict__ Qw,
    const unsigned short* __restrict__ Kw,
    const unsigned short* __restrict__ Vw,
    const int* __restrict__ amask,
    float* __restrict__ out) {
  __shared__ unsigned short Ks[64 * 64];      // [key][d], XOR-swizzled granules within row
  __shared__ unsigned short Vt[64 * 64];      // [d][key] transposed, XOR-swizzled within row
  __shared__ unsigned short Ps[8][16 * 72];   // per-wave P bounce, padded rows

  // XCD-aware swizzle: 768 blocks = 8 XCDs x 96. Each XCD: 3 whole (b,h) heads
  // -> adjacent query chunks' overlapping K/V bands hit the same L2.
  int phys = blockIdx.x;
  int logical = (phys & 7) * 96 + (phys >> 3);
  int qc = logical & 31;   // 32 chunks of 128 queries
  int bh = logical >> 5;   // 0..23
  int b = bh / 12;
  int hh = bh % 12;
  int qbase = qc * 128;

  int t = threadIdx.x, w = t >> 6, l = t & 63;
  int lg = l >> 4, ln = l & 15;

  const unsigned short* Qbh = Qw + (size_t)bh * (NS * 64);
  const unsigned short* Kbh = Kw + (size_t)bh * (NS * 64);
  const unsigned short* Vbh = Vw + (size_t)bh * (NS * 64);
  const int* mrow = amask + b * NS;

  // Q fragments in registers for the whole kernel (A-frag row m = ln -> q = qbase+w*16+ln)
  bf16x8 qf[2];
  {
    const unsigned short* qp = Qbh + (size_t)(qbase + w * 16 + ln) * 64 + lg * 8;
    qf[0] = *reinterpret_cast<const bf16x8*>(qp);
    qf[1] = *reinterpret_cast<const bf16x8*>(qp + 32);
  }

  float m_r[4] = {-1e30f, -1e30f, -1e30f, -1e30f};
  float l_r[4] = {0.f, 0.f, 0.f, 0.f};
  f32x4 oacc[4];
#pragma unroll
  for (int i = 0; i < 4; i++) oacc[i] = f32x4{0.f, 0.f, 0.f, 0.f};

  int q0 = qbase + w * 16 + lg * 4;

  // tt = -1: global tile (keys 0..63, unmasked). tt 0..9: band tiles (640 keys).
  for (int tt = -1; tt < 10; ++tt) {
    int key0 = (tt < 0) ? 0 : (qbase - 256 + tt * 64);
    if (key0 < 0 || key0 >= NS) continue;  // uniform across block

    __syncthreads();
    // --- K stage: global_load_lds, source pre-swizzled so swizzled reads round-trip
    {
      int krow = t >> 3, gran = t & 7;   // 512 chunks of 16B
      gload16(Kbh + (size_t)(key0 + krow) * 64 + (gran ^ (krow & 7)) * 8, Ks + t * 8);
    }
    // --- V stage: reg-load key pairs, write transposed+swizzled as packed b32
    //     element e of row d holds key e ^ ((d&7)<<3); pairs stay adjacent (swizzle bits >= 3)
    {
      int p2 = t & 31;            // key-pair 0..31 -> keys {2p2, 2p2+1}
      int d0 = (t >> 5) * 4;      // 0,4,...,60
      const unsigned short* vp0 = Vbh + (size_t)(key0 + 2 * p2) * 64 + d0;
      u16x4 va = *reinterpret_cast<const u16x4*>(vp0);
      u16x4 vb = *reinterpret_cast<const u16x4*>(vp0 + 64);
#pragma unroll
      for (int j = 0; j < 4; ++j) {
        int d = d0 + j;
        unsigned val = (unsigned)va[j] | ((unsigned)vb[j] << 16);
        *reinterpret_cast<unsigned*>(Vt + d * 64 + ((2 * p2) ^ ((d & 7) << 3))) = val;
      }
    }
    __syncthreads();

    // --- QK^T: S[q][key], D-row = lg*4+r, D-col = nt*16+ln
    f32x4 sa[4];
#pragma unroll
    for (int nt = 0; nt < 4; nt++) sa[nt] = f32x4{0.f, 0.f, 0.f, 0.f};
#pragma unroll
    for (int nt = 0; nt < 4; nt++) {
      int key = nt * 16 + ln;
#pragma unroll
      for (int ks = 0; ks < 2; ++ks) {
        int dby = (ks * 64 + lg * 16) ^ ((key & 7) << 4);
        bf16x8 kf = *reinterpret_cast<const bf16x8*>(Ks + key * 64 + (dby >> 1));
        sa[nt] = __builtin_amdgcn_mfma_f32_16x16x32_bf16(qf[ks], kf, sa[nt], 0, 0, 0);
      }
    }

    // --- masking (band tiles only)
    if (tt >= 0) {
#pragma unroll
      for (int nt = 0; nt < 4; nt++) {
        int ka = key0 + nt * 16 + ln;
        int sup = mrow[ka];
#pragma unroll
        for (int r = 0; r < 4; r++) {
          int qa = q0 + r;
          bool ok = (sup == 0) && (ka >= qa - NW) && (ka <= qa + NW);
          if (!ok) sa[nt][r] = -1e30f;
        }
      }
    }

    // --- online softmax (reduce 4 nt in-lane + 16 lanes via shfl)
    float scl[4];
#pragma unroll
    for (int r = 0; r < 4; r++) {
      float v = fmaxf(fmaxf(sa[0][r], sa[1][r]), fmaxf(sa[2][r], sa[3][r]));
      v = fmaxf(v, __shfl_xor(v, 1, 64));
      v = fmaxf(v, __shfl_xor(v, 2, 64));
      v = fmaxf(v, __shfl_xor(v, 4, 64));
      v = fmaxf(v, __shfl_xor(v, 8, 64));
      float mn = fmaxf(m_r[r], v);
      scl[r] = __expf(m_r[r] - mn);
      m_r[r] = mn;
    }
#pragma unroll
    for (int r = 0; r < 4; r++) {
      float s = 0.f;
#pragma unroll
      for (int nt = 0; nt < 4; nt++) {
        float p = __expf(sa[nt][r] - m_r[r]);
        sa[nt][r] = p;
        s += p;
      }
      s += __shfl_xor(s, 1, 64);
      s += __shfl_xor(s, 2, 64);
      s += __shfl_xor(s, 4, 64);
      s += __shfl_xor(s, 8, 64);
      l_r[r] = l_r[r] * scl[r] + s;
    }
#pragma unroll
    for (int nt = 0; nt < 4; nt++)
#pragma unroll
      for (int r = 0; r < 4; r++) oacc[nt][r] *= scl[r];

    // --- P -> bf16 -> per-wave LDS bounce (row = q within wave, col = key)
    unsigned short* pw = &Ps[w][0];
#pragma unroll
    for (int nt = 0; nt < 4; nt++)
#pragma unroll
      for (int r = 0; r < 4; r++)
        pw[(lg * 4 + r) * 72 + nt * 16 + ln] = f2bf(sa[nt][r]);

    // --- PV: O[q][d] += P[q][keys] @ V[keys][d], V^T read with matching swizzle
#pragma unroll
    for (int ks = 0; ks < 2; ++ks) {
      bf16x8 pf = *reinterpret_cast<const bf16x8*>(pw + ln * 72 + ks * 32 + lg * 8);
#pragma unroll
      for (int nt = 0; nt < 4; ++nt) {
        int d = nt * 16 + ln;
        int eoff = (ks * 32 + lg * 8) ^ ((d & 7) << 3);  // returns keys ks*32+lg*8 .. +7
        bf16x8 vf = *reinterpret_cast<const bf16x8*>(Vt + d * 64 + eoff);
        oacc[nt] = __builtin_amdgcn_mfma_f32_16x16x32_bf16(pf, vf, oacc[nt], 0, 0, 0);
      }
    }
  }

  // --- normalize + write out[(qa*B + b)*768 + h*64 + d] (f32)
#pragma unroll
  for (int nt = 0; nt < 4; nt++) {
    int d = nt * 16 + ln;
#pragma unroll
    for (int r = 0; r < 4; r++) {
      int qa = q0 + r;
      out[((size_t)qa * NB + b) * ND + hh * 64 + d] = oacc[nt][r] / l_r[r];
    }
  }
}

extern "C" void kernel_launch(void* const* d_in, const int* in_sizes, int n_in,
                              void* d_out, int out_size, void* d_ws, size_t ws_size,
                              hipStream_t stream) {
  (void)in_sizes; (void)n_in; (void)out_size; (void)ws_size;
  const float* hidden = (const float*)d_in[0];
  const int*   amask  = (const int*)d_in[1];
  const float* Wq = (const float*)d_in[2];
  const float* bq = (const float*)d_in[3];
  const float* Wk = (const float*)d_in[4];
  const float* bk = (const float*)d_in[5];
  const float* Wv = (const float*)d_in[6];
  const float* bv = (const float*)d_in[7];
  float* out = (float*)d_out;

  char* p = (char*)d_ws;
  unsigned short* hb  = (unsigned short*)p; p += (size_t)8192 * 768 * 2;
  unsigned short* wqb = (unsigned short*)p; p += (size_t)768 * 768 * 2;
  unsigned short* wkb = (unsigned short*)p; p += (size_t)768 * 768 * 2;
  unsigned short* wvb = (unsigned short*)p; p += (size_t)768 * 768 * 2;
  unsigned short* Qws = (unsigned short*)p; p += (size_t)24 * 4096 * 64 * 2;
  unsigned short* Kws = (unsigned short*)p; p += (size_t)24 * 4096 * 64 * 2;
  unsigned short* Vws = (unsigned short*)p; p += (size_t)24 * 4096 * 64 * 2;

  cast_kernel<<<1024, 256, 0, stream>>>(hidden, hb, 8192 * 768 / 4);
  cast3_kernel<<<432, 256, 0, stream>>>(Wq, Wk, Wv, wqb, wkb, wvb);
  qkv_gemm<<<64 * 18, 256, 0, stream>>>(hb, wqb, wkb, wvb, bq, bk, bv, Qws, Kws, Vws);
  attn_kernel<<<24 * 32, 512, 0, stream>>>(Qws, Kws, Vws, amask, out);
}

// Round 4
// 209.678 us; speedup vs baseline: 1.0133x; 1.0133x over previous
//
#include <hip/hip_runtime.h>
#include <hip/hip_bf16.h>
#include <stdint.h>

typedef __attribute__((ext_vector_type(4))) float          f32x4;
typedef __attribute__((ext_vector_type(4))) float          f4;
typedef __attribute__((ext_vector_type(2))) unsigned int   u32x2;
typedef __bf16 bf16_t;
typedef __attribute__((ext_vector_type(8))) bf16_t         bf16x8;
typedef __attribute__((ext_vector_type(8))) unsigned short u16x8;
typedef __attribute__((ext_vector_type(4))) unsigned short u16x4;

#define NB 2
#define NS 4096
#define ND 768
#define NH 12
#define NW 256

__device__ __forceinline__ unsigned short f2bf(float f) {
  union { float f; unsigned u; } v; v.f = f;
  unsigned r = v.u + 0x7fffu + ((v.u >> 16) & 1u);
  return (unsigned short)(r >> 16);
}

__device__ __forceinline__ void gload16(const void* g, void* l) {
  __builtin_amdgcn_global_load_lds((const __attribute__((address_space(1))) void*)g,
                                   (__attribute__((address_space(3))) void*)l, 16, 0, 0);
}

// ---------------- f32 -> bf16 casts ----------------
__global__ void cast_kernel(const float* __restrict__ in, unsigned short* __restrict__ out, int n4) {
  int i = blockIdx.x * blockDim.x + threadIdx.x;
  int stride = gridDim.x * blockDim.x;
  for (; i < n4; i += stride) {
    f4 v = reinterpret_cast<const f4*>(in)[i];
    unsigned u0 = (unsigned)f2bf(v.x) | ((unsigned)f2bf(v.y) << 16);
    unsigned u1 = (unsigned)f2bf(v.z) | ((unsigned)f2bf(v.w) << 16);
    u32x2 o = {u0, u1};
    reinterpret_cast<u32x2*>(out)[i] = o;
  }
}

__global__ void cast3_kernel(const float* __restrict__ w0, const float* __restrict__ w1,
                             const float* __restrict__ w2, unsigned short* __restrict__ o0,
                             unsigned short* __restrict__ o1, unsigned short* __restrict__ o2) {
  const int n4 = 768 * 768 / 4;
  int i = blockIdx.x * blockDim.x + threadIdx.x;
  int stride = gridDim.x * blockDim.x;
  for (; i < 3 * n4; i += stride) {
    int m = i / n4, j = i - m * n4;
    const float* in = (m == 0) ? w0 : ((m == 1) ? w1 : w2);
    unsigned short* out = (m == 0) ? o0 : ((m == 1) ? o1 : o2);
    f4 v = reinterpret_cast<const f4*>(in)[j];
    unsigned u0 = (unsigned)f2bf(v.x) | ((unsigned)f2bf(v.y) << 16);
    unsigned u1 = (unsigned)f2bf(v.z) | ((unsigned)f2bf(v.w) << 16);
    u32x2 o = {u0, u1};
    reinterpret_cast<u32x2*>(out)[j] = o;
  }
}

// ---------------- fused QKV projection GEMM ----------------
__global__ __launch_bounds__(256) void qkv_gemm(
    const unsigned short* __restrict__ Ab,
    const unsigned short* __restrict__ Wqb,
    const unsigned short* __restrict__ Wkb,
    const unsigned short* __restrict__ Wvb,
    const float* __restrict__ bqp, const float* __restrict__ bkp, const float* __restrict__ bvp,
    unsigned short* __restrict__ Qw, unsigned short* __restrict__ Kw, unsigned short* __restrict__ Vw) {
  __shared__ unsigned short As[128 * 32];
  __shared__ unsigned short Bs[128 * 32];

  int phys = blockIdx.x;
  int logical = (phys & 7) * 144 + (phys >> 3);
  int bn = logical % 18, bm = logical / 18;
  int mat = bn / 6, bnn = bn % 6;
  const unsigned short* Wm = (mat == 0) ? Wqb : ((mat == 1) ? Wkb : Wvb);
  const float* bias = (mat == 0) ? bqp : ((mat == 1) ? bkp : bvp);
  unsigned short* dst = (mat == 0) ? Qw : ((mat == 1) ? Kw : Vw);

  int t = threadIdx.x;
  int w = t >> 6, l = t & 63;
  int lg = l >> 4, ln = l & 15;
  int wm = w & 1, wn = w >> 1;

  f32x4 acc[4][4];
#pragma unroll
  for (int i = 0; i < 4; i++)
#pragma unroll
    for (int j = 0; j < 4; j++) acc[i][j] = f32x4{0.f, 0.f, 0.f, 0.f};

  for (int kt = 0; kt < 24; ++kt) {
    __syncthreads();
#pragma unroll
    for (int is = 0; is < 2; ++is) {
      int chunk = is * 256 + t;
      int row = chunk >> 2;
      int c8 = (chunk & 3) * 8;
      gload16(Ab + ((size_t)(bm * 128 + row)) * 768 + kt * 32 + c8, As + chunk * 8);
      gload16(Wm + ((size_t)(bnn * 128 + row)) * 768 + kt * 32 + c8, Bs + chunk * 8);
    }
    __syncthreads();
    bf16x8 af[4], bfr[4];
#pragma unroll
    for (int i = 0; i < 4; i++) {
      af[i]  = *reinterpret_cast<const bf16x8*>(As + (wm * 64 + i * 16 + ln) * 32 + lg * 8);
      bfr[i] = *reinterpret_cast<const bf16x8*>(Bs + (wn * 64 + i * 16 + ln) * 32 + lg * 8);
    }
#pragma unroll
    for (int i = 0; i < 4; i++)
#pragma unroll
      for (int j = 0; j < 4; j++)
        acc[i][j] = __builtin_amdgcn_mfma_f32_16x16x32_bf16(af[i], bfr[j], acc[i][j], 0, 0, 0);
  }

#pragma unroll
  for (int j = 0; j < 4; j++) {
    int col = bnn * 128 + wn * 64 + j * 16 + ln;
    float bv_ = bias[col];
    int hh = col >> 6, dd = col & 63;
#pragma unroll
    for (int i = 0; i < 4; i++) {
#pragma unroll
      for (int r = 0; r < 4; r++) {
        int tok = bm * 128 + wm * 64 + i * 16 + lg * 4 + r;
        int bb = tok >> 12, ss = tok & 4095;
        float v = acc[i][j][r] + bv_;
        if (mat == 0) v *= 0.125f;
        dst[(((size_t)bb * 12 + hh) * 4096 + ss) * 64 + dd] = f2bf(v);
      }
    }
  }
}

// ---------------- fused band + global attention ----------------
// 1 block = (b,h, 128-query chunk). 8 waves x 16 query rows. Double-buffered
// K/V staging: one barrier per tile, next tile's loads issued before compute.
__global__ __launch_bounds__(512) void attn_kernel(
    const unsigned short* __restrict__ Qw,
    const unsigned short* __restrict__ Kw,
    const unsigned short* __restrict__ Vw,
    const int* __restrict__ amask,
    float* __restrict__ out) {
  __shared__ unsigned short Ks[2][64 * 64];   // [key][d], XOR-swizzled granules
  __shared__ unsigned short Vt[2][64 * 64];   // [d][key] transposed, XOR-swizzled
  __shared__ unsigned short Ps[8][16 * 72];   // per-wave P bounce
  __shared__ unsigned Msk[128];               // 4096-bit suppression mask

  int phys = blockIdx.x;
  int logical = (phys & 7) * 96 + (phys >> 3);  // XCD-contiguous heads
  int qc = logical & 31;
  int bh = logical >> 5;
  int b = bh / 12;
  int hh = bh % 12;
  int qbase = qc * 128;

  int t = threadIdx.x, w = t >> 6, l = t & 63;
  int lg = l >> 4, ln = l & 15;

  const unsigned short* Qbh = Qw + (size_t)bh * (NS * 64);
  const unsigned short* Kbh = Kw + (size_t)bh * (NS * 64);
  const unsigned short* Vbh = Vw + (size_t)bh * (NS * 64);
  const int* mrow = amask + b * NS;

  // one-time mask bitfield: word i covers keys 32i..32i+31
#pragma unroll
  for (int r8 = 0; r8 < 8; ++r8) {
    int wp = r8 * 8 + w;                    // 0..63, 64 keys each
    unsigned long long bal = __ballot(mrow[wp * 64 + l] != 0);
    if (l == 0) {
      Msk[wp * 2] = (unsigned)bal;
      Msk[wp * 2 + 1] = (unsigned)(bal >> 32);
    }
  }

  // Q fragments in registers (A-frag row = ln -> q = qbase + w*16 + ln)
  bf16x8 qf[2];
  {
    const unsigned short* qp = Qbh + (size_t)(qbase + w * 16 + ln) * 64 + lg * 8;
    qf[0] = *reinterpret_cast<const bf16x8*>(qp);
    qf[1] = *reinterpret_cast<const bf16x8*>(qp + 32);
  }

  float m_r[4] = {-1e30f, -1e30f, -1e30f, -1e30f};
  float l_r[4] = {0.f, 0.f, 0.f, 0.f};
  f32x4 oacc[4];
#pragma unroll
  for (int i = 0; i < 4; i++) oacc[i] = f32x4{0.f, 0.f, 0.f, 0.f};

  int q0 = qbase + w * 16 + lg * 4;

  // tile schedule: idx 0 = global keys 0..63; idx>=1 = band tiles tt_lo..tt_hi
  int tt_lo = (qbase >= 256) ? 0 : ((256 - qbase) >> 6);
  int tt_hi_raw = (NS + 192 - qbase) >> 6;
  int tt_hi = tt_hi_raw < 9 ? tt_hi_raw : 9;
  int ntl = tt_hi - tt_lo + 2;

  int krow = t >> 3, gran = t & 7;          // K staging coords
  int p2 = t & 31, d0v = (t >> 5) * 4;      // V staging coords

  // prologue: stage tile 0 (global keys) into buffer 0
  {
    gload16(Kbh + (size_t)krow * 64 + (gran ^ (krow & 7)) * 8, &Ks[0][0] + t * 8);
    const unsigned short* vp0 = Vbh + (size_t)(2 * p2) * 64 + d0v;
    u16x4 va = *reinterpret_cast<const u16x4*>(vp0);
    u16x4 vb = *reinterpret_cast<const u16x4*>(vp0 + 64);
#pragma unroll
    for (int j = 0; j < 4; ++j) {
      int d = d0v + j;
      unsigned val = (unsigned)va[j] | ((unsigned)vb[j] << 16);
      *reinterpret_cast<unsigned*>(&Vt[0][0] + d * 64 + ((2 * p2) ^ ((d & 7) << 3))) = val;
    }
  }
  __syncthreads();

  for (int idx = 0; idx < ntl; ++idx) {
    int cur = idx & 1;
    int key0 = (idx == 0) ? 0 : (qbase - 256 + (tt_lo + idx - 1) * 64);
    bool has_next = (idx + 1) < ntl;

    // ---- issue next tile's loads (K -> LDS async, V -> regs) before compute
    u16x4 va, vb;
    if (has_next) {
      int nk0 = qbase - 256 + (tt_lo + idx) * 64;
      gload16(Kbh + (size_t)(nk0 + krow) * 64 + (gran ^ (krow & 7)) * 8,
              &Ks[cur ^ 1][0] + t * 8);
      const unsigned short* vp0 = Vbh + (size_t)(nk0 + 2 * p2) * 64 + d0v;
      va = *reinterpret_cast<const u16x4*>(vp0);
      vb = *reinterpret_cast<const u16x4*>(vp0 + 64);
    }

    // ---- QK^T on buffer cur
    const unsigned short* ksb = &Ks[cur][0];
    f32x4 sa[4];
#pragma unroll
    for (int nt = 0; nt < 4; nt++) sa[nt] = f32x4{0.f, 0.f, 0.f, 0.f};
#pragma unroll
    for (int nt = 0; nt < 4; nt++) {
      int key = nt * 16 + ln;
#pragma unroll
      for (int ks = 0; ks < 2; ++ks) {
        int dby = (ks * 64 + lg * 16) ^ ((key & 7) << 4);
        bf16x8 kf = *reinterpret_cast<const bf16x8*>(ksb + key * 64 + (dby >> 1));
        sa[nt] = __builtin_amdgcn_mfma_f32_16x16x32_bf16(qf[ks], kf, sa[nt], 0, 0, 0);
      }
    }

    // ---- masking (band tiles): suppression bit from LDS + band-range check
    if (idx > 0) {
#pragma unroll
      for (int nt = 0; nt < 4; nt++) {
        int ka = key0 + nt * 16 + ln;
        bool sup = (Msk[ka >> 5] >> (ka & 31)) & 1;
#pragma unroll
        for (int r = 0; r < 4; r++) {
          bool bad = sup || ((unsigned)(ka - (q0 + r) + NW) > 2u * NW);
          if (bad) sa[nt][r] = -1e30f;
        }
      }
    }

    // ---- online softmax
    float scl[4];
#pragma unroll
    for (int r = 0; r < 4; r++) {
      float v = fmaxf(fmaxf(sa[0][r], sa[1][r]), fmaxf(sa[2][r], sa[3][r]));
      v = fmaxf(v, __shfl_xor(v, 1, 64));
      v = fmaxf(v, __shfl_xor(v, 2, 64));
      v = fmaxf(v, __shfl_xor(v, 4, 64));
      v = fmaxf(v, __shfl_xor(v, 8, 64));
      float mn = fmaxf(m_r[r], v);
      scl[r] = __expf(m_r[r] - mn);
      m_r[r] = mn;
    }
#pragma unroll
    for (int r = 0; r < 4; r++) {
      float s = 0.f;
#pragma unroll
      for (int nt = 0; nt < 4; nt++) {
        float p = __expf(sa[nt][r] - m_r[r]);
        sa[nt][r] = p;
        s += p;
      }
      s += __shfl_xor(s, 1, 64);
      s += __shfl_xor(s, 2, 64);
      s += __shfl_xor(s, 4, 64);
      s += __shfl_xor(s, 8, 64);
      l_r[r] = l_r[r] * scl[r] + s;
    }
#pragma unroll
    for (int nt = 0; nt < 4; nt++)
#pragma unroll
      for (int r = 0; r < 4; r++) oacc[nt][r] *= scl[r];

    // ---- P -> bf16 -> per-wave LDS bounce
    unsigned short* pw = &Ps[w][0];
#pragma unroll
    for (int nt = 0; nt < 4; nt++)
#pragma unroll
      for (int r = 0; r < 4; r++) {
        __hip_bfloat16 hb = __float2bfloat16(sa[nt][r]);
        pw[(lg * 4 + r) * 72 + nt * 16 + ln] = *reinterpret_cast<unsigned short*>(&hb);
      }

    // ---- PV from buffer cur
    const unsigned short* vtb = &Vt[cur][0];
#pragma unroll
    for (int ks = 0; ks < 2; ++ks) {
      bf16x8 pf = *reinterpret_cast<const bf16x8*>(pw + ln * 72 + ks * 32 + lg * 8);
#pragma unroll
      for (int nt = 0; nt < 4; ++nt) {
        int d = nt * 16 + ln;
        int eoff = (ks * 32 + lg * 8) ^ ((d & 7) << 3);
        bf16x8 vf = *reinterpret_cast<const bf16x8*>(vtb + d * 64 + eoff);
        oacc[nt] = __builtin_amdgcn_mfma_f32_16x16x32_bf16(pf, vf, oacc[nt], 0, 0, 0);
      }
    }

    // ---- land prefetched V into the other buffer (waits its vmcnt here)
    if (has_next) {
      unsigned short* vtn = &Vt[cur ^ 1][0];
#pragma unroll
      for (int j = 0; j < 4; ++j) {
        int d = d0v + j;
        unsigned val = (unsigned)va[j] | ((unsigned)vb[j] << 16);
        *reinterpret_cast<unsigned*>(vtn + d * 64 + ((2 * p2) ^ ((d & 7) << 3))) = val;
      }
    }
    __syncthreads();  // drains K gload_lds (vmcnt) + V ds_writes; flips buffers
  }

  // ---- normalize + write out[(qa*B + b)*768 + h*64 + d] (f32)
#pragma unroll
  for (int nt = 0; nt < 4; nt++) {
    int d = nt * 16 + ln;
#pragma unroll
    for (int r = 0; r < 4; r++) {
      int qa = q0 + r;
      out[((size_t)qa * NB + b) * ND + hh * 64 + d] = oacc[nt][r] / l_r[r];
    }
  }
}

extern "C" void kernel_launch(void* const* d_in, const int* in_sizes, int n_in,
                              void* d_out, int out_size, void* d_ws, size_t ws_size,
                              hipStream_t stream) {
  (void)in_sizes; (void)n_in; (void)out_size; (void)ws_size;
  const float* hidden = (const float*)d_in[0];
  const int*   amask  = (const int*)d_in[1];
  const float* Wq = (const float*)d_in[2];
  const float* bq = (const float*)d_in[3];
  const float* Wk = (const float*)d_in[4];
  const float* bk = (const float*)d_in[5];
  const float* Wv = (const float*)d_in[6];
  const float* bv = (const float*)d_in[7];
  float* out = (float*)d_out;

  char* p = (char*)d_ws;
  unsigned short* hb  = (unsigned short*)p; p += (size_t)8192 * 768 * 2;
  unsigned short* wqb = (unsigned short*)p; p += (size_t)768 * 768 * 2;
  unsigned short* wkb = (unsigned short*)p; p += (size_t)768 * 768 * 2;
  unsigned short* wvb = (unsigned short*)p; p += (size_t)768 * 768 * 2;
  unsigned short* Qws = (unsigned short*)p; p += (size_t)24 * 4096 * 64 * 2;
  unsigned short* Kws = (unsigned short*)p; p += (size_t)24 * 4096 * 64 * 2;
  unsigned short* Vws = (unsigned short*)p; p += (size_t)24 * 4096 * 64 * 2;

  cast_kernel<<<1024, 256, 0, stream>>>(hidden, hb, 8192 * 768 / 4);
  cast3_kernel<<<432, 256, 0, stream>>>(Wq, Wk, Wv, wqb, wkb, wvb);
  qkv_gemm<<<64 * 18, 256, 0, stream>>>(hb, wqb, wkb, wvb, bq, bk, bv, Qws, Kws, Vws);
  attn_kernel<<<24 * 32, 512, 0, stream>>>(Qws, Kws, Vws, amask, out);
}

// Round 5
// 201.627 us; speedup vs baseline: 1.0538x; 1.0399x over previous
//
#include <hip/hip_runtime.h>
#include <hip/hip_bf16.h>
#include <stdint.h>

typedef __attribute__((ext_vector_type(4))) float          f32x4;
typedef __attribute__((ext_vector_type(4))) float          f4;
typedef __attribute__((ext_vector_type(2))) unsigned int   u32x2;
typedef __bf16 bf16_t;
typedef __attribute__((ext_vector_type(8))) bf16_t         bf16x8;
typedef __attribute__((ext_vector_type(8))) unsigned short u16x8;
typedef __attribute__((ext_vector_type(4))) unsigned short u16x4;

#define NB 2
#define NS 4096
#define ND 768
#define NH 12
#define NW 256

__device__ __forceinline__ unsigned short f2bf(float f) {
  union { float f; unsigned u; } v; v.f = f;
  unsigned r = v.u + 0x7fffu + ((v.u >> 16) & 1u);
  return (unsigned short)(r >> 16);
}

__device__ __forceinline__ unsigned pack2bf(float a, float b) {
  return (unsigned)f2bf(a) | ((unsigned)f2bf(b) << 16);
}

__device__ __forceinline__ void gload16(const void* g, void* l) {
  __builtin_amdgcn_global_load_lds((const __attribute__((address_space(1))) void*)g,
                                   (__attribute__((address_space(3))) void*)l, 16, 0, 0);
}

// ---------------- f32 -> bf16 casts ----------------
__global__ void cast_kernel(const float* __restrict__ in, unsigned short* __restrict__ out, int n4) {
  int i = blockIdx.x * blockDim.x + threadIdx.x;
  int stride = gridDim.x * blockDim.x;
  for (; i < n4; i += stride) {
    f4 v = reinterpret_cast<const f4*>(in)[i];
    u32x2 o = {pack2bf(v.x, v.y), pack2bf(v.z, v.w)};
    reinterpret_cast<u32x2*>(out)[i] = o;
  }
}

__global__ void cast3_kernel(const float* __restrict__ w0, const float* __restrict__ w1,
                             const float* __restrict__ w2, unsigned short* __restrict__ o0,
                             unsigned short* __restrict__ o1, unsigned short* __restrict__ o2) {
  const int n4 = 768 * 768 / 4;
  int i = blockIdx.x * blockDim.x + threadIdx.x;
  int stride = gridDim.x * blockDim.x;
  for (; i < 3 * n4; i += stride) {
    int m = i / n4, j = i - m * n4;
    const float* in = (m == 0) ? w0 : ((m == 1) ? w1 : w2);
    unsigned short* out = (m == 0) ? o0 : ((m == 1) ? o1 : o2);
    f4 v = reinterpret_cast<const f4*>(in)[j];
    u32x2 o = {pack2bf(v.x, v.y), pack2bf(v.z, v.w)};
    reinterpret_cast<u32x2*>(out)[j] = o;
  }
}

// ---------------- fused QKV projection GEMM ----------------
__global__ __launch_bounds__(256) void qkv_gemm(
    const unsigned short* __restrict__ Ab,
    const unsigned short* __restrict__ Wqb,
    const unsigned short* __restrict__ Wkb,
    const unsigned short* __restrict__ Wvb,
    const float* __restrict__ bqp, const float* __restrict__ bkp, const float* __restrict__ bvp,
    unsigned short* __restrict__ Qw, unsigned short* __restrict__ Kw, unsigned short* __restrict__ Vw) {
  __shared__ unsigned short As[128 * 32];
  __shared__ unsigned short Bs[128 * 32];

  int phys = blockIdx.x;
  int logical = (phys & 7) * 144 + (phys >> 3);
  int bn = logical % 18, bm = logical / 18;
  int mat = bn / 6, bnn = bn % 6;
  const unsigned short* Wm = (mat == 0) ? Wqb : ((mat == 1) ? Wkb : Wvb);
  const float* bias = (mat == 0) ? bqp : ((mat == 1) ? bkp : bvp);
  unsigned short* dst = (mat == 0) ? Qw : ((mat == 1) ? Kw : Vw);

  int t = threadIdx.x;
  int w = t >> 6, l = t & 63;
  int lg = l >> 4, ln = l & 15;
  int wm = w & 1, wn = w >> 1;

  f32x4 acc[4][4];
#pragma unroll
  for (int i = 0; i < 4; i++)
#pragma unroll
    for (int j = 0; j < 4; j++) acc[i][j] = f32x4{0.f, 0.f, 0.f, 0.f};

  for (int kt = 0; kt < 24; ++kt) {
    __syncthreads();
#pragma unroll
    for (int is = 0; is < 2; ++is) {
      int chunk = is * 256 + t;
      int row = chunk >> 2;
      int c8 = (chunk & 3) * 8;
      gload16(Ab + ((size_t)(bm * 128 + row)) * 768 + kt * 32 + c8, As + chunk * 8);
      gload16(Wm + ((size_t)(bnn * 128 + row)) * 768 + kt * 32 + c8, Bs + chunk * 8);
    }
    __syncthreads();
    bf16x8 af[4], bfr[4];
#pragma unroll
    for (int i = 0; i < 4; i++) {
      af[i]  = *reinterpret_cast<const bf16x8*>(As + (wm * 64 + i * 16 + ln) * 32 + lg * 8);
      bfr[i] = *reinterpret_cast<const bf16x8*>(Bs + (wn * 64 + i * 16 + ln) * 32 + lg * 8);
    }
#pragma unroll
    for (int i = 0; i < 4; i++)
#pragma unroll
      for (int j = 0; j < 4; j++)
        acc[i][j] = __builtin_amdgcn_mfma_f32_16x16x32_bf16(af[i], bfr[j], acc[i][j], 0, 0, 0);
  }

  // epilogue: bias; Q additionally scaled by (1/8)*log2(e) so attention works in exp2 domain
#pragma unroll
  for (int j = 0; j < 4; j++) {
    int col = bnn * 128 + wn * 64 + j * 16 + ln;
    float bv_ = bias[col];
    int hh = col >> 6, dd = col & 63;
#pragma unroll
    for (int i = 0; i < 4; i++) {
#pragma unroll
      for (int r = 0; r < 4; r++) {
        int tok = bm * 128 + wm * 64 + i * 16 + lg * 4 + r;
        int bb = tok >> 12, ss = tok & 4095;
        float v = acc[i][j][r] + bv_;
        if (mat == 0) v *= 0.1803368801111244f;  // 0.125 * log2(e)
        dst[(((size_t)bb * 12 + hh) * 4096 + ss) * 64 + dd] = f2bf(v);
      }
    }
  }
}

// ---------------- fused band + global attention (swapped-QK structure) ----------------
// 1 block = (b,h, 128-query chunk). 8 waves x 16 q-columns each.
// S^T = mfma(K, Q): lane (ln,lg) holds S[key=16nt+4lg+r][q=ln] -> softmax is
// in-lane + 2 shfl_xor; packed P words feed PV's B-operand directly (permuted
// k-order), V^T read in matching order via 2x ds_read_b64. No P LDS bounce.
__global__ __launch_bounds__(512) void attn_kernel(
    const unsigned short* __restrict__ Qw,
    const unsigned short* __restrict__ Kw,
    const unsigned short* __restrict__ Vw,
    const int* __restrict__ amask,
    float* __restrict__ out) {
  __shared__ unsigned short Ks[2][64 * 64];   // [key][d], XOR-swizzled granules
  __shared__ unsigned short Vt[2][64 * 64];   // [d][key] transposed, XOR-swizzled
  __shared__ unsigned Msk[128];               // 4096-bit suppression mask

  int phys = blockIdx.x;
  int logical = (phys & 7) * 96 + (phys >> 3);  // XCD-contiguous heads
  int qc = logical & 31;
  int bh = logical >> 5;
  int b = bh / 12;
  int hh = bh % 12;
  int qbase = qc * 128;

  int t = threadIdx.x, w = t >> 6, l = t & 63;
  int lg = l >> 4, ln = l & 15;

  const unsigned short* Qbh = Qw + (size_t)bh * (NS * 64);
  const unsigned short* Kbh = Kw + (size_t)bh * (NS * 64);
  const unsigned short* Vbh = Vw + (size_t)bh * (NS * 64);
  const int* mrow = amask + b * NS;

  // one-time mask bitfield: word i covers keys 32i..32i+31
#pragma unroll
  for (int r8 = 0; r8 < 8; ++r8) {
    int wp = r8 * 8 + w;
    unsigned long long bal = __ballot(mrow[wp * 64 + l] != 0);
    if (l == 0) {
      Msk[wp * 2] = (unsigned)bal;
      Msk[wp * 2 + 1] = (unsigned)(bal >> 32);
    }
  }

  int q = qbase + w * 16 + ln;   // this lane's q column
  int qwmin = qbase + w * 16;

  // Q fragments (B-operand: lane holds Q[q=ln][d=ks*32+lg*8..+7]) - same load as before
  bf16x8 qf[2];
  {
    const unsigned short* qp = Qbh + (size_t)q * 64 + lg * 8;
    qf[0] = *reinterpret_cast<const bf16x8*>(qp);
    qf[1] = *reinterpret_cast<const bf16x8*>(qp + 32);
  }

  float m_s = -1e30f, l_s = 0.f;
  f32x4 oacc[4];
#pragma unroll
  for (int i = 0; i < 4; i++) oacc[i] = f32x4{0.f, 0.f, 0.f, 0.f};

  // tile schedule: idx 0 = global keys 0..63; idx>=1 = band tiles tt_lo..tt_hi
  int tt_lo = (qbase >= 256) ? 0 : ((256 - qbase) >> 6);
  int tt_hi_raw = (NS + 192 - qbase) >> 6;
  int tt_hi = tt_hi_raw < 9 ? tt_hi_raw : 9;
  int ntl = tt_hi - tt_lo + 2;

  int krow = t >> 3, gran = t & 7;          // K staging coords
  int p2 = t & 31, d0v = (t >> 5) * 4;      // V staging coords

  // prologue: stage tile 0 (global keys) into buffer 0
  {
    gload16(Kbh + (size_t)krow * 64 + (gran ^ (krow & 7)) * 8, &Ks[0][0] + t * 8);
    const unsigned short* vp0 = Vbh + (size_t)(2 * p2) * 64 + d0v;
    u16x4 va = *reinterpret_cast<const u16x4*>(vp0);
    u16x4 vb = *reinterpret_cast<const u16x4*>(vp0 + 64);
#pragma unroll
    for (int j = 0; j < 4; ++j) {
      int d = d0v + j;
      unsigned val = (unsigned)va[j] | ((unsigned)vb[j] << 16);
      *reinterpret_cast<unsigned*>(&Vt[0][0] + d * 64 + ((2 * p2) ^ ((d & 7) << 3))) = val;
    }
  }
  __syncthreads();

  for (int idx = 0; idx < ntl; ++idx) {
    int cur = idx & 1;
    int key0 = (idx == 0) ? 0 : (qbase - 256 + (tt_lo + idx - 1) * 64);
    bool has_next = (idx + 1) < ntl;

    // ---- issue next tile's loads (K -> LDS async, V -> regs) before compute
    u16x4 va, vb;
    if (has_next) {
      int nk0 = qbase - 256 + (tt_lo + idx) * 64;
      gload16(Kbh + (size_t)(nk0 + krow) * 64 + (gran ^ (krow & 7)) * 8,
              &Ks[cur ^ 1][0] + t * 8);
      const unsigned short* vp0 = Vbh + (size_t)(nk0 + 2 * p2) * 64 + d0v;
      va = *reinterpret_cast<const u16x4*>(vp0);
      vb = *reinterpret_cast<const u16x4*>(vp0 + 64);
    }

    // ---- S^T = K @ Q^T on buffer cur: sa[nt] reg r = S[key0+16nt+4lg+r][q]
    const unsigned short* ksb = &Ks[cur][0];
    f32x4 sa[4];
#pragma unroll
    for (int nt = 0; nt < 4; nt++) sa[nt] = f32x4{0.f, 0.f, 0.f, 0.f};
#pragma unroll
    for (int nt = 0; nt < 4; nt++) {
      int key = nt * 16 + ln;
#pragma unroll
      for (int ks = 0; ks < 2; ++ks) {
        int dby = (ks * 64 + lg * 16) ^ ((key & 7) << 4);
        bf16x8 kf = *reinterpret_cast<const bf16x8*>(ksb + key * 64 + (dby >> 1));
        sa[nt] = __builtin_amdgcn_mfma_f32_16x16x32_bf16(kf, qf[ks], sa[nt], 0, 0, 0);
      }
    }

    // ---- masking (band tiles, skipped for clean interior tiles)
    if (idx > 0) {
      unsigned mw0 = Msk[key0 >> 5], mw1 = Msk[(key0 >> 5) + 1];
      bool clean = ((mw0 | mw1) == 0) && (key0 >= qwmin - 241) && (key0 <= qwmin + 193);
      if (!clean) {
#pragma unroll
        for (int nt = 0; nt < 4; nt++) {
          unsigned mword = (nt & 2) ? mw1 : mw0;
#pragma unroll
          for (int r = 0; r < 4; r++) {
            int key = key0 + 16 * nt + 4 * lg + r;
            bool sup = (mword >> ((16 * (nt & 1) + 4 * lg + r) & 31)) & 1;
            bool bad = sup || ((unsigned)(key - q + NW) > 2u * NW);
            if (bad) sa[nt][r] = -1e30f;
          }
        }
      }
    }

    // ---- online softmax over keys (in-lane 16 + 2 shfl); defer-max (T13)
    float tmax = sa[0][0];
#pragma unroll
    for (int nt = 0; nt < 4; nt++)
#pragma unroll
      for (int r = 0; r < 4; r++) tmax = fmaxf(tmax, sa[nt][r]);
    tmax = fmaxf(tmax, __shfl_xor(tmax, 16, 64));
    tmax = fmaxf(tmax, __shfl_xor(tmax, 32, 64));
    if (!__all(tmax - m_s <= 8.f)) {
      float mn = fmaxf(m_s, tmax);
      float scl = exp2f(m_s - mn);
      m_s = mn;
      l_s *= scl;
#pragma unroll
      for (int i = 0; i < 4; i++) oacc[i] *= scl;
    }
    float ssum = 0.f;
#pragma unroll
    for (int nt = 0; nt < 4; nt++)
#pragma unroll
      for (int r = 0; r < 4; r++) {
        float p = exp2f(sa[nt][r] - m_s);
        sa[nt][r] = p;
        ssum += p;
      }
    ssum += __shfl_xor(ssum, 16, 64);
    ssum += __shfl_xor(ssum, 32, 64);
    l_s += ssum;

    // ---- pack P to bf16 pairs (keys 16nt+4lg+2p,+1 | q=ln) - stays in registers
    unsigned pk[4][2];
#pragma unroll
    for (int nt = 0; nt < 4; nt++) {
      pk[nt][0] = pack2bf(sa[nt][0], sa[nt][1]);
      pk[nt][1] = pack2bf(sa[nt][2], sa[nt][3]);
    }

    // ---- PV: O^T += V^T @ P^T. B-operand = pk words directly (permuted k-order);
    //      A-operand = V^T rows read in the SAME permuted order (2x b64 per frag).
    const unsigned short* vtb = &Vt[cur][0];
#pragma unroll
    for (int ks = 0; ks < 2; ++ks) {
      union { unsigned u[4]; bf16x8 v; } pf;
      pf.u[0] = pk[2 * ks][0];
      pf.u[1] = pk[2 * ks][1];
      pf.u[2] = pk[2 * ks + 1][0];
      pf.u[3] = pk[2 * ks + 1][1];
#pragma unroll
      for (int nt = 0; nt < 4; ++nt) {
        int d = nt * 16 + ln;
        int sw = (d & 7) << 3;
        int e0 = (32 * ks + 4 * lg) ^ sw;
        int e1 = (32 * ks + 16 + 4 * lg) ^ sw;
        union { u16x4 h[2]; bf16x8 v; } vf;
        vf.h[0] = *reinterpret_cast<const u16x4*>(vtb + d * 64 + e0);
        vf.h[1] = *reinterpret_cast<const u16x4*>(vtb + d * 64 + e1);
        oacc[nt] = __builtin_amdgcn_mfma_f32_16x16x32_bf16(vf.v, pf.v, oacc[nt], 0, 0, 0);
      }
    }

    // ---- land prefetched V into the other buffer
    if (has_next) {
      unsigned short* vtn = &Vt[cur ^ 1][0];
#pragma unroll
      for (int j = 0; j < 4; ++j) {
        int d = d0v + j;
        unsigned val = (unsigned)va[j] | ((unsigned)vb[j] << 16);
        *reinterpret_cast<unsigned*>(vtn + d * 64 + ((2 * p2) ^ ((d & 7) << 3))) = val;
      }
    }
    __syncthreads();
  }

  // ---- normalize + vectorized write: lane owns q; d = nt*16+4lg+{0..3}
  float inv = 1.0f / l_s;
  float* orow = out + ((size_t)q * NB + b) * ND + hh * 64;
#pragma unroll
  for (int nt = 0; nt < 4; nt++) {
    f4 o;
#pragma unroll
    for (int r = 0; r < 4; r++) o[r] = oacc[nt][r] * inv;
    *reinterpret_cast<f4*>(orow + nt * 16 + 4 * lg) = o;
  }
}

extern "C" void kernel_launch(void* const* d_in, const int* in_sizes, int n_in,
                              void* d_out, int out_size, void* d_ws, size_t ws_size,
                              hipStream_t stream) {
  (void)in_sizes; (void)n_in; (void)out_size; (void)ws_size;
  const float* hidden = (const float*)d_in[0];
  const int*   amask  = (const int*)d_in[1];
  const float* Wq = (const float*)d_in[2];
  const float* bq = (const float*)d_in[3];
  const float* Wk = (const float*)d_in[4];
  const float* bk = (const float*)d_in[5];
  const float* Wv = (const float*)d_in[6];
  const float* bv = (const float*)d_in[7];
  float* out = (float*)d_out;

  char* p = (char*)d_ws;
  unsigned short* hb  = (unsigned short*)p; p += (size_t)8192 * 768 * 2;
  unsigned short* wqb = (unsigned short*)p; p += (size_t)768 * 768 * 2;
  unsigned short* wkb = (unsigned short*)p; p += (size_t)768 * 768 * 2;
  unsigned short* wvb = (unsigned short*)p; p += (size_t)768 * 768 * 2;
  unsigned short* Qws = (unsigned short*)p; p += (size_t)24 * 4096 * 64 * 2;
  unsigned short* Kws = (unsigned short*)p; p += (size_t)24 * 4096 * 64 * 2;
  unsigned short* Vws = (unsigned short*)p; p += (size_t)24 * 4096 * 64 * 2;

  cast_kernel<<<1024, 256, 0, stream>>>(hidden, hb, 8192 * 768 / 4);
  cast3_kernel<<<432, 256, 0, stream>>>(Wq, Wk, Wv, wqb, wkb, wvb);
  qkv_gemm<<<64 * 18, 256, 0, stream>>>(hb, wqb, wkb, wvb, bq, bk, bv, Qws, Kws, Vws);
  attn_kernel<<<24 * 32, 512, 0, stream>>>(Qws, Kws, Vws, amask, out);
}

// Round 6
// 196.527 us; speedup vs baseline: 1.0811x; 1.0260x over previous
//
#include <hip/hip_runtime.h>
#include <hip/hip_bf16.h>
#include <stdint.h>

typedef __attribute__((ext_vector_type(4))) float          f32x4;
typedef __attribute__((ext_vector_type(4))) float          f4;
typedef __attribute__((ext_vector_type(2))) unsigned int   u32x2;
typedef __bf16 bf16_t;
typedef __attribute__((ext_vector_type(8))) bf16_t         bf16x8;
typedef __attribute__((ext_vector_type(8))) unsigned short u16x8;
typedef __attribute__((ext_vector_type(4))) unsigned short u16x4;

#define NB 2
#define NS 4096
#define ND 768
#define NH 12
#define NW 256

__device__ __forceinline__ unsigned short f2bf(float f) {
  union { float f; unsigned u; } v; v.f = f;
  unsigned r = v.u + 0x7fffu + ((v.u >> 16) & 1u);
  return (unsigned short)(r >> 16);
}

__device__ __forceinline__ unsigned pack2bf(float a, float b) {
  return (unsigned)f2bf(a) | ((unsigned)f2bf(b) << 16);
}

__device__ __forceinline__ void gload16(const void* g, void* l) {
  __builtin_amdgcn_global_load_lds((const __attribute__((address_space(1))) void*)g,
                                   (__attribute__((address_space(3))) void*)l, 16, 0, 0);
}

// ---------------- f32 -> bf16 casts ----------------
__global__ void cast_kernel(const float* __restrict__ in, unsigned short* __restrict__ out, int n4) {
  int i = blockIdx.x * blockDim.x + threadIdx.x;
  int stride = gridDim.x * blockDim.x;
  for (; i < n4; i += stride) {
    f4 v = reinterpret_cast<const f4*>(in)[i];
    u32x2 o = {pack2bf(v.x, v.y), pack2bf(v.z, v.w)};
    reinterpret_cast<u32x2*>(out)[i] = o;
  }
}

__global__ void cast3_kernel(const float* __restrict__ w0, const float* __restrict__ w1,
                             const float* __restrict__ w2, unsigned short* __restrict__ o0,
                             unsigned short* __restrict__ o1, unsigned short* __restrict__ o2) {
  const int n4 = 768 * 768 / 4;
  int i = blockIdx.x * blockDim.x + threadIdx.x;
  int stride = gridDim.x * blockDim.x;
  for (; i < 3 * n4; i += stride) {
    int m = i / n4, j = i - m * n4;
    const float* in = (m == 0) ? w0 : ((m == 1) ? w1 : w2);
    unsigned short* out = (m == 0) ? o0 : ((m == 1) ? o1 : o2);
    f4 v = reinterpret_cast<const f4*>(in)[j];
    u32x2 o = {pack2bf(v.x, v.y), pack2bf(v.z, v.w)};
    reinterpret_cast<u32x2*>(out)[j] = o;
  }
}

// ---------------- fused QKV projection GEMM (frozen this round) ----------------
__global__ __launch_bounds__(256) void qkv_gemm(
    const unsigned short* __restrict__ Ab,
    const unsigned short* __restrict__ Wqb,
    const unsigned short* __restrict__ Wkb,
    const unsigned short* __restrict__ Wvb,
    const float* __restrict__ bqp, const float* __restrict__ bkp, const float* __restrict__ bvp,
    unsigned short* __restrict__ Qw, unsigned short* __restrict__ Kw, unsigned short* __restrict__ Vw) {
  __shared__ unsigned short As[128 * 32];
  __shared__ unsigned short Bs[128 * 32];

  int phys = blockIdx.x;
  int logical = (phys & 7) * 144 + (phys >> 3);
  int bn = logical % 18, bm = logical / 18;
  int mat = bn / 6, bnn = bn % 6;
  const unsigned short* Wm = (mat == 0) ? Wqb : ((mat == 1) ? Wkb : Wvb);
  const float* bias = (mat == 0) ? bqp : ((mat == 1) ? bkp : bvp);
  unsigned short* dst = (mat == 0) ? Qw : ((mat == 1) ? Kw : Vw);

  int t = threadIdx.x;
  int w = t >> 6, l = t & 63;
  int lg = l >> 4, ln = l & 15;
  int wm = w & 1, wn = w >> 1;

  f32x4 acc[4][4];
#pragma unroll
  for (int i = 0; i < 4; i++)
#pragma unroll
    for (int j = 0; j < 4; j++) acc[i][j] = f32x4{0.f, 0.f, 0.f, 0.f};

  for (int kt = 0; kt < 24; ++kt) {
    __syncthreads();
#pragma unroll
    for (int is = 0; is < 2; ++is) {
      int chunk = is * 256 + t;
      int row = chunk >> 2;
      int c8 = (chunk & 3) * 8;
      gload16(Ab + ((size_t)(bm * 128 + row)) * 768 + kt * 32 + c8, As + chunk * 8);
      gload16(Wm + ((size_t)(bnn * 128 + row)) * 768 + kt * 32 + c8, Bs + chunk * 8);
    }
    __syncthreads();
    bf16x8 af[4], bfr[4];
#pragma unroll
    for (int i = 0; i < 4; i++) {
      af[i]  = *reinterpret_cast<const bf16x8*>(As + (wm * 64 + i * 16 + ln) * 32 + lg * 8);
      bfr[i] = *reinterpret_cast<const bf16x8*>(Bs + (wn * 64 + i * 16 + ln) * 32 + lg * 8);
    }
#pragma unroll
    for (int i = 0; i < 4; i++)
#pragma unroll
      for (int j = 0; j < 4; j++)
        acc[i][j] = __builtin_amdgcn_mfma_f32_16x16x32_bf16(af[i], bfr[j], acc[i][j], 0, 0, 0);
  }

  // epilogue: bias; Q additionally scaled by (1/8)*log2(e) so attention works in exp2 domain
#pragma unroll
  for (int j = 0; j < 4; j++) {
    int col = bnn * 128 + wn * 64 + j * 16 + ln;
    float bv_ = bias[col];
    int hh = col >> 6, dd = col & 63;
#pragma unroll
    for (int i = 0; i < 4; i++) {
#pragma unroll
      for (int r = 0; r < 4; r++) {
        int tok = bm * 128 + wm * 64 + i * 16 + lg * 4 + r;
        int bb = tok >> 12, ss = tok & 4095;
        float v = acc[i][j][r] + bv_;
        if (mat == 0) v *= 0.1803368801111244f;  // 0.125 * log2(e)
        dst[(((size_t)bb * 12 + hh) * 4096 + ss) * 64 + dd] = f2bf(v);
      }
    }
  }
}

// ---------------- fused band + global attention (swapped-QK structure) ----------------
// 1 block = (b,h, 128-query chunk). 8 waves x 16 q-columns each.
// S^T = mfma(K, Q): lane (ln,lg) holds S[key=16nt+4lg+r][q=ln]. Softmax in-lane;
// l_s kept as per-lane partial (reduced once at end). P packed in regs feeds PV
// B-operand directly. V^T swizzle granule = 4 elems: conflict-free b64 reads.
__global__ __launch_bounds__(512) void attn_kernel(
    const unsigned short* __restrict__ Qw,
    const unsigned short* __restrict__ Kw,
    const unsigned short* __restrict__ Vw,
    const int* __restrict__ amask,
    float* __restrict__ out) {
  __shared__ unsigned short Ks[2][64 * 64];   // [key][d], XOR-swizzled 8-elem granules
  __shared__ unsigned short Vt[2][64 * 64];   // [d][key], XOR-swizzled 4-elem granules
  __shared__ unsigned Msk[128];               // 4096-bit suppression mask

  int phys = blockIdx.x;
  int logical = (phys & 7) * 96 + (phys >> 3);  // XCD-contiguous heads
  int qc = logical & 31;
  int bh = logical >> 5;
  int b = bh / 12;
  int hh = bh % 12;
  int qbase = qc * 128;

  int t = threadIdx.x, w = t >> 6, l = t & 63;
  int lg = l >> 4, ln = l & 15;

  const unsigned short* Qbh = Qw + (size_t)bh * (NS * 64);
  const unsigned short* Kbh = Kw + (size_t)bh * (NS * 64);
  const unsigned short* Vbh = Vw + (size_t)bh * (NS * 64);
  const int* mrow = amask + b * NS;

  // one-time mask bitfield: word i covers keys 32i..32i+31
#pragma unroll
  for (int r8 = 0; r8 < 8; ++r8) {
    int wp = r8 * 8 + w;
    unsigned long long bal = __ballot(mrow[wp * 64 + l] != 0);
    if (l == 0) {
      Msk[wp * 2] = (unsigned)bal;
      Msk[wp * 2 + 1] = (unsigned)(bal >> 32);
    }
  }

  int q = qbase + w * 16 + ln;   // this lane's q column
  int qwmin = qbase + w * 16;

  bf16x8 qf[2];
  {
    const unsigned short* qp = Qbh + (size_t)q * 64 + lg * 8;
    qf[0] = *reinterpret_cast<const bf16x8*>(qp);
    qf[1] = *reinterpret_cast<const bf16x8*>(qp + 32);
  }

  float m_s = -1e30f, l_s = 0.f;   // l_s: PARTIAL (this lane's 16 key-slots only)
  f32x4 oacc[4];
#pragma unroll
  for (int i = 0; i < 4; i++) oacc[i] = f32x4{0.f, 0.f, 0.f, 0.f};

  int tt_lo = (qbase >= 256) ? 0 : ((256 - qbase) >> 6);
  int tt_hi_raw = (NS + 192 - qbase) >> 6;
  int tt_hi = tt_hi_raw < 9 ? tt_hi_raw : 9;
  int ntl = tt_hi - tt_lo + 2;

  int krow = t >> 3, gran = t & 7;          // K staging coords
  int p2 = t & 31, d0v = (t >> 5) * 4;      // V staging coords

  // prologue: stage tile 0 (global keys) into buffer 0
  {
    gload16(Kbh + (size_t)krow * 64 + (gran ^ (krow & 7)) * 8, &Ks[0][0] + t * 8);
    const unsigned short* vp0 = Vbh + (size_t)(2 * p2) * 64 + d0v;
    u16x4 va = *reinterpret_cast<const u16x4*>(vp0);
    u16x4 vb = *reinterpret_cast<const u16x4*>(vp0 + 64);
#pragma unroll
    for (int j = 0; j < 4; ++j) {
      int d = d0v + j;
      unsigned val = (unsigned)va[j] | ((unsigned)vb[j] << 16);
      *reinterpret_cast<unsigned*>(&Vt[0][0] + d * 64 + ((2 * p2) ^ ((d & 15) << 2))) = val;
    }
  }
  __syncthreads();

  for (int idx = 0; idx < ntl; ++idx) {
    int cur = idx & 1;
    int key0 = (idx == 0) ? 0 : (qbase - 256 + (tt_lo + idx - 1) * 64);
    bool has_next = (idx + 1) < ntl;

    // ---- issue next tile's loads (K -> LDS async, V -> regs) before compute
    u16x4 va, vb;
    if (has_next) {
      int nk0 = qbase - 256 + (tt_lo + idx) * 64;
      gload16(Kbh + (size_t)(nk0 + krow) * 64 + (gran ^ (krow & 7)) * 8,
              &Ks[cur ^ 1][0] + t * 8);
      const unsigned short* vp0 = Vbh + (size_t)(nk0 + 2 * p2) * 64 + d0v;
      va = *reinterpret_cast<const u16x4*>(vp0);
      vb = *reinterpret_cast<const u16x4*>(vp0 + 64);
    }

    // ---- per-wave tile relevance: skip compute on tiles outside this wave's band
    bool relevant = (idx == 0) ||
                    ((key0 + 63 >= qwmin - 256) && (key0 <= qwmin + 15 + 256));
    if (relevant) {
      // ---- S^T = K @ Q^T: sa[nt] reg r = S[key0+16nt+4lg+r][q]
      const unsigned short* ksb = &Ks[cur][0];
      f32x4 sa[4];
#pragma unroll
      for (int nt = 0; nt < 4; nt++) sa[nt] = f32x4{0.f, 0.f, 0.f, 0.f};
#pragma unroll
      for (int nt = 0; nt < 4; nt++) {
        int key = nt * 16 + ln;
#pragma unroll
        for (int ks = 0; ks < 2; ++ks) {
          int dby = (ks * 64 + lg * 16) ^ ((key & 7) << 4);
          bf16x8 kf = *reinterpret_cast<const bf16x8*>(ksb + key * 64 + (dby >> 1));
          sa[nt] = __builtin_amdgcn_mfma_f32_16x16x32_bf16(kf, qf[ks], sa[nt], 0, 0, 0);
        }
      }

      // ---- masking (band tiles; skipped on clean interior tiles)
      if (idx > 0) {
        unsigned mw0 = Msk[key0 >> 5], mw1 = Msk[(key0 >> 5) + 1];
        bool clean = ((mw0 | mw1) == 0) && (key0 >= qwmin - 241) && (key0 <= qwmin + 193);
        if (!clean) {
#pragma unroll
          for (int nt = 0; nt < 4; nt++) {
            unsigned mword = (nt & 2) ? mw1 : mw0;
#pragma unroll
            for (int r = 0; r < 4; r++) {
              int key = key0 + 16 * nt + 4 * lg + r;
              bool sup = (mword >> ((16 * (nt & 1) + 4 * lg + r) & 31)) & 1;
              bool bad = sup || ((unsigned)(key - q + NW) > 2u * NW);
              if (bad) sa[nt][r] = -1e30f;
            }
          }
        }
      }

      // ---- online softmax: in-lane max; shfl-reduce ONLY when rescale triggers
      float tmax = sa[0][0];
#pragma unroll
      for (int nt = 0; nt < 4; nt++)
#pragma unroll
        for (int r = 0; r < 4; r++) tmax = fmaxf(tmax, sa[nt][r]);
      if (!__all(tmax - m_s <= 8.f)) {
        tmax = fmaxf(tmax, __shfl_xor(tmax, 16, 64));
        tmax = fmaxf(tmax, __shfl_xor(tmax, 32, 64));
        float mn = fmaxf(m_s, tmax);
        float scl = exp2f(m_s - mn);
        m_s = mn;
        l_s *= scl;
#pragma unroll
        for (int i = 0; i < 4; i++) oacc[i] *= scl;
      }
#pragma unroll
      for (int nt = 0; nt < 4; nt++)
#pragma unroll
        for (int r = 0; r < 4; r++) {
          float p = exp2f(sa[nt][r] - m_s);
          sa[nt][r] = p;
          l_s += p;
        }

      // ---- pack P to bf16 pairs - stays in registers
      unsigned pk[4][2];
#pragma unroll
      for (int nt = 0; nt < 4; nt++) {
        pk[nt][0] = pack2bf(sa[nt][0], sa[nt][1]);
        pk[nt][1] = pack2bf(sa[nt][2], sa[nt][3]);
      }

      // ---- PV: O^T += V^T @ P^T (A = V^T rows in permuted k-order, granule-4 swizzle)
      const unsigned short* vtb = &Vt[cur][0];
#pragma unroll
      for (int ks = 0; ks < 2; ++ks) {
        union { unsigned u[4]; bf16x8 v; } pf;
        pf.u[0] = pk[2 * ks][0];
        pf.u[1] = pk[2 * ks][1];
        pf.u[2] = pk[2 * ks + 1][0];
        pf.u[3] = pk[2 * ks + 1][1];
#pragma unroll
        for (int nt = 0; nt < 4; ++nt) {
          int d = nt * 16 + ln;
          int sw = (d & 15) << 2;
          int e0 = (32 * ks + 4 * lg) ^ sw;
          int e1 = (32 * ks + 16 + 4 * lg) ^ sw;
          union { u16x4 h[2]; bf16x8 v; } vf;
          vf.h[0] = *reinterpret_cast<const u16x4*>(vtb + d * 64 + e0);
          vf.h[1] = *reinterpret_cast<const u16x4*>(vtb + d * 64 + e1);
          oacc[nt] = __builtin_amdgcn_mfma_f32_16x16x32_bf16(vf.v, pf.v, oacc[nt], 0, 0, 0);
        }
      }
    }

    // ---- land prefetched V into the other buffer
    if (has_next) {
      unsigned short* vtn = &Vt[cur ^ 1][0];
#pragma unroll
      for (int j = 0; j < 4; ++j) {
        int d = d0v + j;
        unsigned val = (unsigned)va[j] | ((unsigned)vb[j] << 16);
        *reinterpret_cast<unsigned*>(vtn + d * 64 + ((2 * p2) ^ ((d & 15) << 2))) = val;
      }
    }
    __syncthreads();
  }

  // ---- finalize: reduce partial l_s across the 4 lg lanes of each q, write out
  l_s += __shfl_xor(l_s, 16, 64);
  l_s += __shfl_xor(l_s, 32, 64);
  float inv = 1.0f / l_s;
  float* orow = out + ((size_t)q * NB + b) * ND + hh * 64;
#pragma unroll
  for (int nt = 0; nt < 4; nt++) {
    f4 o;
#pragma unroll
    for (int r = 0; r < 4; r++) o[r] = oacc[nt][r] * inv;
    *reinterpret_cast<f4*>(orow + nt * 16 + 4 * lg) = o;
  }
}

extern "C" void kernel_launch(void* const* d_in, const int* in_sizes, int n_in,
                              void* d_out, int out_size, void* d_ws, size_t ws_size,
                              hipStream_t stream) {
  (void)in_sizes; (void)n_in; (void)out_size; (void)ws_size;
  const float* hidden = (const float*)d_in[0];
  const int*   amask  = (const int*)d_in[1];
  const float* Wq = (const float*)d_in[2];
  const float* bq = (const float*)d_in[3];
  const float* Wk = (const float*)d_in[4];
  const float* bk = (const float*)d_in[5];
  const float* Wv = (const float*)d_in[6];
  const float* bv = (const float*)d_in[7];
  float* out = (float*)d_out;

  char* p = (char*)d_ws;
  unsigned short* hb  = (unsigned short*)p; p += (size_t)8192 * 768 * 2;
  unsigned short* wqb = (unsigned short*)p; p += (size_t)768 * 768 * 2;
  unsigned short* wkb = (unsigned short*)p; p += (size_t)768 * 768 * 2;
  unsigned short* wvb = (unsigned short*)p; p += (size_t)768 * 768 * 2;
  unsigned short* Qws = (unsigned short*)p; p += (size_t)24 * 4096 * 64 * 2;
  unsigned short* Kws = (unsigned short*)p; p += (size_t)24 * 4096 * 64 * 2;
  unsigned short* Vws = (unsigned short*)p; p += (size_t)24 * 4096 * 64 * 2;

  cast_kernel<<<1024, 256, 0, stream>>>(hidden, hb, 8192 * 768 / 4);
  cast3_kernel<<<432, 256, 0, stream>>>(Wq, Wk, Wv, wqb, wkb, wvb);
  qkv_gemm<<<64 * 18, 256, 0, stream>>>(hb, wqb, wkb, wvb, bq, bk, bv, Qws, Kws, Vws);
  attn_kernel<<<24 * 32, 512, 0, stream>>>(Qws, Kws, Vws, amask, out);
}

// Round 7
// 193.032 us; speedup vs baseline: 1.1007x; 1.0181x over previous
//
#include <hip/hip_runtime.h>
#include <hip/hip_bf16.h>
#include <stdint.h>

typedef __attribute__((ext_vector_type(4))) float          f32x4;
typedef __attribute__((ext_vector_type(4))) float          f4;
typedef __attribute__((ext_vector_type(2))) unsigned int   u32x2;
typedef __bf16 bf16_t;
typedef __attribute__((ext_vector_type(8))) bf16_t         bf16x8;
typedef __attribute__((ext_vector_type(8))) unsigned short u16x8;
typedef __attribute__((ext_vector_type(4))) unsigned short u16x4;

#define NB 2
#define NS 4096
#define ND 768
#define NH 12
#define NW 256

__device__ __forceinline__ unsigned short f2bf(float f) {
  union { float f; unsigned u; } v; v.f = f;
  unsigned r = v.u + 0x7fffu + ((v.u >> 16) & 1u);
  return (unsigned short)(r >> 16);
}

__device__ __forceinline__ unsigned pack2bf(float a, float b) {
  return (unsigned)f2bf(a) | ((unsigned)f2bf(b) << 16);
}

// raw v_exp_f32: exp2(x). Safe here: defer-max bounds x <= 8; x = -1e30 -> 0.
__device__ __forceinline__ float exp2_fast(float x) {
  float r;
  asm("v_exp_f32 %0, %1" : "=v"(r) : "v"(x));
  return r;
}

__device__ __forceinline__ void gload16(const void* g, void* l) {
  __builtin_amdgcn_global_load_lds((const __attribute__((address_space(1))) void*)g,
                                   (__attribute__((address_space(3))) void*)l, 16, 0, 0);
}

// ---------------- f32 -> bf16 casts ----------------
__global__ void cast_kernel(const float* __restrict__ in, unsigned short* __restrict__ out, int n4) {
  int i = blockIdx.x * blockDim.x + threadIdx.x;
  int stride = gridDim.x * blockDim.x;
  for (; i < n4; i += stride) {
    f4 v = reinterpret_cast<const f4*>(in)[i];
    u32x2 o = {pack2bf(v.x, v.y), pack2bf(v.z, v.w)};
    reinterpret_cast<u32x2*>(out)[i] = o;
  }
}

__global__ void cast3_kernel(const float* __restrict__ w0, const float* __restrict__ w1,
                             const float* __restrict__ w2, unsigned short* __restrict__ o0,
                             unsigned short* __restrict__ o1, unsigned short* __restrict__ o2) {
  const int n4 = 768 * 768 / 4;
  int i = blockIdx.x * blockDim.x + threadIdx.x;
  int stride = gridDim.x * blockDim.x;
  for (; i < 3 * n4; i += stride) {
    int m = i / n4, j = i - m * n4;
    const float* in = (m == 0) ? w0 : ((m == 1) ? w1 : w2);
    unsigned short* out = (m == 0) ? o0 : ((m == 1) ? o1 : o2);
    f4 v = reinterpret_cast<const f4*>(in)[j];
    u32x2 o = {pack2bf(v.x, v.y), pack2bf(v.z, v.w)};
    reinterpret_cast<u32x2*>(out)[j] = o;
  }
}

// ---------------- fused QKV projection GEMM ----------------
// Double-buffered staging, ONE barrier per K-step; LDS-bounce epilogue with
// 16B-granule swizzle -> coalesced b128 stores.
__global__ __launch_bounds__(256) void qkv_gemm(
    const unsigned short* __restrict__ Ab,
    const unsigned short* __restrict__ Wqb,
    const unsigned short* __restrict__ Wkb,
    const unsigned short* __restrict__ Wvb,
    const float* __restrict__ bqp, const float* __restrict__ bkp, const float* __restrict__ bvp,
    unsigned short* __restrict__ Qw, unsigned short* __restrict__ Kw, unsigned short* __restrict__ Vw) {
  __shared__ unsigned short smem[2][2][128 * 32];   // [buf][A/B][row*32+k] ; aliased by epilogue

  int phys = blockIdx.x;
  int logical = (phys & 7) * 144 + (phys >> 3);
  int bn = logical % 18, bm = logical / 18;
  int mat = bn / 6, bnn = bn % 6;
  const unsigned short* Wm = (mat == 0) ? Wqb : ((mat == 1) ? Wkb : Wvb);
  const float* bias = (mat == 0) ? bqp : ((mat == 1) ? bkp : bvp);
  unsigned short* dst = (mat == 0) ? Qw : ((mat == 1) ? Kw : Vw);

  int t = threadIdx.x;
  int w = t >> 6, l = t & 63;
  int lg = l >> 4, ln = l & 15;
  int wm = w & 1, wn = w >> 1;

  f32x4 acc[4][4];
#pragma unroll
  for (int i = 0; i < 4; i++)
#pragma unroll
    for (int j = 0; j < 4; j++) acc[i][j] = f32x4{0.f, 0.f, 0.f, 0.f};

  // prologue: stage kt=0 into buffer 0
#pragma unroll
  for (int is = 0; is < 2; ++is) {
    int chunk = is * 256 + t;
    int row = chunk >> 2;
    int c8 = (chunk & 3) * 8;
    gload16(Ab + ((size_t)(bm * 128 + row)) * 768 + c8, &smem[0][0][chunk * 8]);
    gload16(Wm + ((size_t)(bnn * 128 + row)) * 768 + c8, &smem[0][1][chunk * 8]);
  }
  __syncthreads();

  for (int kt = 0; kt < 24; ++kt) {
    int cur = kt & 1;
    if (kt < 23) {
#pragma unroll
      for (int is = 0; is < 2; ++is) {
        int chunk = is * 256 + t;
        int row = chunk >> 2;
        int c8 = (chunk & 3) * 8;
        gload16(Ab + ((size_t)(bm * 128 + row)) * 768 + (kt + 1) * 32 + c8,
                &smem[cur ^ 1][0][chunk * 8]);
        gload16(Wm + ((size_t)(bnn * 128 + row)) * 768 + (kt + 1) * 32 + c8,
                &smem[cur ^ 1][1][chunk * 8]);
      }
    }
    bf16x8 af[4], bfr[4];
#pragma unroll
    for (int i = 0; i < 4; i++) {
      af[i]  = *reinterpret_cast<const bf16x8*>(&smem[cur][0][(wm * 64 + i * 16 + ln) * 32 + lg * 8]);
      bfr[i] = *reinterpret_cast<const bf16x8*>(&smem[cur][1][(wn * 64 + i * 16 + ln) * 32 + lg * 8]);
    }
#pragma unroll
    for (int i = 0; i < 4; i++)
#pragma unroll
      for (int j = 0; j < 4; j++)
        acc[i][j] = __builtin_amdgcn_mfma_f32_16x16x32_bf16(af[i], bfr[j], acc[i][j], 0, 0, 0);
    __syncthreads();   // drains vmcnt (next-tile gloads) + protects buffer reuse
  }

  // epilogue: bias (+ Q scale), bf16, bounce through swizzled 128x128 LDS tile
  unsigned short* ep = &smem[0][0][0];   // 128 rows x 128 cols, granule-16B ^ (row&15)
#pragma unroll
  for (int j = 0; j < 4; j++) {
    int col = wn * 64 + j * 16 + ln;          // within-tile col
    float bv_ = bias[bnn * 128 + col];
#pragma unroll
    for (int i = 0; i < 4; i++) {
#pragma unroll
      for (int r = 0; r < 4; r++) {
        int row = wm * 64 + i * 16 + lg * 4 + r;
        float v = acc[i][j][r] + bv_;
        if (mat == 0) v *= 0.1803368801111244f;  // 0.125 * log2(e)
        int g = col >> 3;
        ep[row * 128 + (((g ^ (row & 15)) << 3) | (col & 7))] = f2bf(v);
      }
    }
  }
  __syncthreads();
  {
    int row = t >> 1, half = t & 1;
    int tok = bm * 128 + row;
    int bb = tok >> 12, ss = tok & 4095;
    int head = bnn * 2 + half;
    unsigned short* drow = dst + (((size_t)bb * 12 + head) * 4096 + ss) * 64;
#pragma unroll
    for (int kk8 = 0; kk8 < 8; ++kk8) {
      int g = (half * 8 + kk8) ^ (row & 15);
      *reinterpret_cast<u16x8*>(drow + kk8 * 8) =
          *reinterpret_cast<const u16x8*>(ep + row * 128 + g * 8);
    }
  }
}

// ---------------- fused band + global attention (swapped-QK structure) ----------------
__global__ __launch_bounds__(512) void attn_kernel(
    const unsigned short* __restrict__ Qw,
    const unsigned short* __restrict__ Kw,
    const unsigned short* __restrict__ Vw,
    const int* __restrict__ amask,
    float* __restrict__ out) {
  __shared__ unsigned short Ks[2][64 * 64];   // [key][d], XOR-swizzled 8-elem granules
  __shared__ unsigned short Vt[2][64 * 64];   // [d][key], XOR-swizzled 4-elem granules
  __shared__ unsigned Msk[128];               // 4096-bit suppression mask

  int phys = blockIdx.x;
  int logical = (phys & 7) * 96 + (phys >> 3);  // XCD-contiguous heads
  int qc = logical & 31;
  int bh = logical >> 5;
  int b = bh / 12;
  int hh = bh % 12;
  int qbase = qc * 128;

  int t = threadIdx.x, w = t >> 6, l = t & 63;
  int lg = l >> 4, ln = l & 15;

  const unsigned short* Qbh = Qw + (size_t)bh * (NS * 64);
  const unsigned short* Kbh = Kw + (size_t)bh * (NS * 64);
  const unsigned short* Vbh = Vw + (size_t)bh * (NS * 64);
  const int* mrow = amask + b * NS;

#pragma unroll
  for (int r8 = 0; r8 < 8; ++r8) {
    int wp = r8 * 8 + w;
    unsigned long long bal = __ballot(mrow[wp * 64 + l] != 0);
    if (l == 0) {
      Msk[wp * 2] = (unsigned)bal;
      Msk[wp * 2 + 1] = (unsigned)(bal >> 32);
    }
  }

  int q = qbase + w * 16 + ln;   // this lane's q column
  int qwmin = qbase + w * 16;

  bf16x8 qf[2];
  {
    const unsigned short* qp = Qbh + (size_t)q * 64 + lg * 8;
    qf[0] = *reinterpret_cast<const bf16x8*>(qp);
    qf[1] = *reinterpret_cast<const bf16x8*>(qp + 32);
  }

  float m_s = -1e30f, l_s = 0.f;   // l_s: per-lane partial, reduced at the end
  f32x4 oacc[4];
#pragma unroll
  for (int i = 0; i < 4; i++) oacc[i] = f32x4{0.f, 0.f, 0.f, 0.f};

  int tt_lo = (qbase >= 256) ? 0 : ((256 - qbase) >> 6);
  int tt_hi_raw = (NS + 192 - qbase) >> 6;
  int tt_hi = tt_hi_raw < 9 ? tt_hi_raw : 9;
  int ntl = tt_hi - tt_lo + 2;

  int krow = t >> 3, gran = t & 7;          // K staging coords
  int p2 = t & 31, d0v = (t >> 5) * 4;      // V staging coords

  // prologue: stage tile 0 (global keys) into buffer 0
  {
    gload16(Kbh + (size_t)krow * 64 + (gran ^ (krow & 7)) * 8, &Ks[0][0] + t * 8);
    const unsigned short* vp0 = Vbh + (size_t)(2 * p2) * 64 + d0v;
    u16x4 va = *reinterpret_cast<const u16x4*>(vp0);
    u16x4 vb = *reinterpret_cast<const u16x4*>(vp0 + 64);
#pragma unroll
    for (int j = 0; j < 4; ++j) {
      int d = d0v + j;
      unsigned val = (unsigned)va[j] | ((unsigned)vb[j] << 16);
      *reinterpret_cast<unsigned*>(&Vt[0][0] + d * 64 + ((2 * p2) ^ ((d & 15) << 2))) = val;
    }
  }
  __syncthreads();

  for (int idx = 0; idx < ntl; ++idx) {
    int cur = idx & 1;
    int key0 = (idx == 0) ? 0 : (qbase - 256 + (tt_lo + idx - 1) * 64);
    bool has_next = (idx + 1) < ntl;

    // ---- issue next tile's loads (K -> LDS async, V -> regs) before compute
    u16x4 va, vb;
    if (has_next) {
      int nk0 = qbase - 256 + (tt_lo + idx) * 64;
      gload16(Kbh + (size_t)(nk0 + krow) * 64 + (gran ^ (krow & 7)) * 8,
              &Ks[cur ^ 1][0] + t * 8);
      const unsigned short* vp0 = Vbh + (size_t)(nk0 + 2 * p2) * 64 + d0v;
      va = *reinterpret_cast<const u16x4*>(vp0);
      vb = *reinterpret_cast<const u16x4*>(vp0 + 64);
    }

    // ---- per-wave tile relevance
    bool relevant = (idx == 0) ||
                    ((key0 + 63 >= qwmin - 256) && (key0 <= qwmin + 15 + 256));
    if (relevant) {
      // ---- S^T = K @ Q^T: sa[nt] reg r = S[key0+16nt+4lg+r][q]
      const unsigned short* ksb = &Ks[cur][0];
      f32x4 sa[4];
#pragma unroll
      for (int nt = 0; nt < 4; nt++) sa[nt] = f32x4{0.f, 0.f, 0.f, 0.f};
#pragma unroll
      for (int nt = 0; nt < 4; nt++) {
        int key = nt * 16 + ln;
#pragma unroll
        for (int ks = 0; ks < 2; ++ks) {
          int dby = (ks * 64 + lg * 16) ^ ((key & 7) << 4);
          bf16x8 kf = *reinterpret_cast<const bf16x8*>(ksb + key * 64 + (dby >> 1));
          sa[nt] = __builtin_amdgcn_mfma_f32_16x16x32_bf16(kf, qf[ks], sa[nt], 0, 0, 0);
        }
      }

      // ---- masking (band tiles; skipped on clean interior tiles)
      if (idx > 0) {
        unsigned mw0 = Msk[key0 >> 5], mw1 = Msk[(key0 >> 5) + 1];
        bool clean = ((mw0 | mw1) == 0) && (key0 >= qwmin - 241) && (key0 <= qwmin + 193);
        if (!clean) {
#pragma unroll
          for (int nt = 0; nt < 4; nt++) {
            unsigned mword = (nt & 2) ? mw1 : mw0;
#pragma unroll
            for (int r = 0; r < 4; r++) {
              int key = key0 + 16 * nt + 4 * lg + r;
              bool sup = (mword >> ((16 * (nt & 1) + 4 * lg + r) & 31)) & 1;
              bool bad = sup || ((unsigned)(key - q + NW) > 2u * NW);
              if (bad) sa[nt][r] = -1e30f;
            }
          }
        }
      }

      // ---- online softmax: in-lane max; shfl-reduce only on rescale trigger
      float tmax = sa[0][0];
#pragma unroll
      for (int nt = 0; nt < 4; nt++)
#pragma unroll
        for (int r = 0; r < 4; r++) tmax = fmaxf(tmax, sa[nt][r]);
      if (!__all(tmax - m_s <= 8.f)) {
        tmax = fmaxf(tmax, __shfl_xor(tmax, 16, 64));
        tmax = fmaxf(tmax, __shfl_xor(tmax, 32, 64));
        float mn = fmaxf(m_s, tmax);
        float scl = exp2_fast(m_s - mn);
        m_s = mn;
        l_s *= scl;
#pragma unroll
        for (int i = 0; i < 4; i++) oacc[i] *= scl;
      }
#pragma unroll
      for (int nt = 0; nt < 4; nt++)
#pragma unroll
        for (int r = 0; r < 4; r++) {
          float p = exp2_fast(sa[nt][r] - m_s);
          sa[nt][r] = p;
          l_s += p;
        }

      // ---- P -> bf16 (compiler emits v_cvt_pk_bf16_f32), stays in registers
      union { bf16_t bb[8]; bf16x8 v; } pf0, pf1;
#pragma unroll
      for (int r = 0; r < 4; r++) {
        pf0.bb[r]     = (bf16_t)sa[0][r];
        pf0.bb[4 + r] = (bf16_t)sa[1][r];
        pf1.bb[r]     = (bf16_t)sa[2][r];
        pf1.bb[4 + r] = (bf16_t)sa[3][r];
      }

      // ---- PV: O^T += V^T @ P^T (A = V^T rows, granule-4 swizzle, conflict-free)
      const unsigned short* vtb = &Vt[cur][0];
#pragma unroll
      for (int ks = 0; ks < 2; ++ks) {
        bf16x8 pv = ks ? pf1.v : pf0.v;
#pragma unroll
        for (int nt = 0; nt < 4; ++nt) {
          int d = nt * 16 + ln;
          int sw = (d & 15) << 2;
          int e0 = (32 * ks + 4 * lg) ^ sw;
          int e1 = (32 * ks + 16 + 4 * lg) ^ sw;
          union { u16x4 h[2]; bf16x8 v; } vf;
          vf.h[0] = *reinterpret_cast<const u16x4*>(vtb + d * 64 + e0);
          vf.h[1] = *reinterpret_cast<const u16x4*>(vtb + d * 64 + e1);
          oacc[nt] = __builtin_amdgcn_mfma_f32_16x16x32_bf16(vf.v, pv, oacc[nt], 0, 0, 0);
        }
      }
    }

    // ---- land prefetched V into the other buffer
    if (has_next) {
      unsigned short* vtn = &Vt[cur ^ 1][0];
#pragma unroll
      for (int j = 0; j < 4; ++j) {
        int d = d0v + j;
        unsigned val = (unsigned)va[j] | ((unsigned)vb[j] << 16);
        *reinterpret_cast<unsigned*>(vtn + d * 64 + ((2 * p2) ^ ((d & 15) << 2))) = val;
      }
    }
    __syncthreads();
  }

  // ---- finalize: reduce partial l_s across the 4 lanes sharing this q
  l_s += __shfl_xor(l_s, 16, 64);
  l_s += __shfl_xor(l_s, 32, 64);
  float inv = 1.0f / l_s;
  float* orow = out + ((size_t)q * NB + b) * ND + hh * 64;
#pragma unroll
  for (int nt = 0; nt < 4; nt++) {
    f4 o;
#pragma unroll
    for (int r = 0; r < 4; r++) o[r] = oacc[nt][r] * inv;
    *reinterpret_cast<f4*>(orow + nt * 16 + 4 * lg) = o;
  }
}

extern "C" void kernel_launch(void* const* d_in, const int* in_sizes, int n_in,
                              void* d_out, int out_size, void* d_ws, size_t ws_size,
                              hipStream_t stream) {
  (void)in_sizes; (void)n_in; (void)out_size; (void)ws_size;
  const float* hidden = (const float*)d_in[0];
  const int*   amask  = (const int*)d_in[1];
  const float* Wq = (const float*)d_in[2];
  const float* bq = (const float*)d_in[3];
  const float* Wk = (const float*)d_in[4];
  const float* bk = (const float*)d_in[5];
  const float* Wv = (const float*)d_in[6];
  const float* bv = (const float*)d_in[7];
  float* out = (float*)d_out;

  char* p = (char*)d_ws;
  unsigned short* hb  = (unsigned short*)p; p += (size_t)8192 * 768 * 2;
  unsigned short* wqb = (unsigned short*)p; p += (size_t)768 * 768 * 2;
  unsigned short* wkb = (unsigned short*)p; p += (size_t)768 * 768 * 2;
  unsigned short* wvb = (unsigned short*)p; p += (size_t)768 * 768 * 2;
  unsigned short* Qws = (unsigned short*)p; p += (size_t)24 * 4096 * 64 * 2;
  unsigned short* Kws = (unsigned short*)p; p += (size_t)24 * 4096 * 64 * 2;
  unsigned short* Vws = (unsigned short*)p; p += (size_t)24 * 4096 * 64 * 2;

  cast_kernel<<<1024, 256, 0, stream>>>(hidden, hb, 8192 * 768 / 4);
  cast3_kernel<<<432, 256, 0, stream>>>(Wq, Wk, Wv, wqb, wkb, wvb);
  qkv_gemm<<<64 * 18, 256, 0, stream>>>(hb, wqb, wkb, wvb, bq, bk, bv, Qws, Kws, Vws);
  attn_kernel<<<24 * 32, 512, 0, stream>>>(Qws, Kws, Vws, amask, out);
}

// Round 8
// 188.834 us; speedup vs baseline: 1.1252x; 1.0222x over previous
//
#include <hip/hip_runtime.h>
#include <hip/hip_bf16.h>
#include <stdint.h>

typedef __attribute__((ext_vector_type(4))) float          f32x4;
typedef __attribute__((ext_vector_type(4))) float          f4;
typedef __attribute__((ext_vector_type(2))) unsigned int   u32x2;
typedef __bf16 bf16_t;
typedef __attribute__((ext_vector_type(8))) bf16_t         bf16x8;
typedef __attribute__((ext_vector_type(8))) unsigned short u16x8;
typedef __attribute__((ext_vector_type(4))) unsigned short u16x4;

#define NB 2
#define NS 4096
#define ND 768
#define NH 12
#define NW 256

__device__ __forceinline__ unsigned short f2bf(float f) {
  union { float f; unsigned u; } v; v.f = f;
  unsigned r = v.u + 0x7fffu + ((v.u >> 16) & 1u);
  return (unsigned short)(r >> 16);
}

__device__ __forceinline__ unsigned pack2bf(float a, float b) {
  return (unsigned)f2bf(a) | ((unsigned)f2bf(b) << 16);
}

// raw v_exp_f32: exp2(x). Safe here: defer-max bounds x <= 8; x = -1e30 -> 0.
__device__ __forceinline__ float exp2_fast(float x) {
  float r;
  asm("v_exp_f32 %0, %1" : "=v"(r) : "v"(x));
  return r;
}

__device__ __forceinline__ void gload16(const void* g, void* l) {
  __builtin_amdgcn_global_load_lds((const __attribute__((address_space(1))) void*)g,
                                   (__attribute__((address_space(3))) void*)l, 16, 0, 0);
}

// ---------------- all f32 -> bf16 casts in one launch ----------------
__global__ void cast_all(const float* __restrict__ hidden,
                         const float* __restrict__ w0, const float* __restrict__ w1,
                         const float* __restrict__ w2,
                         unsigned short* __restrict__ hb,
                         unsigned short* __restrict__ o0, unsigned short* __restrict__ o1,
                         unsigned short* __restrict__ o2) {
  const int nh4 = 8192 * 768 / 4;
  const int nw4 = 768 * 768 / 4;
  const int total = nh4 + 3 * nw4;
  int i = blockIdx.x * blockDim.x + threadIdx.x;
  int stride = gridDim.x * blockDim.x;
  for (; i < total; i += stride) {
    const float* in; unsigned short* out; int j;
    if (i < nh4) { in = hidden; out = hb; j = i; }
    else {
      int k = i - nh4, m = k / nw4;
      j = k - m * nw4;
      in = (m == 0) ? w0 : ((m == 1) ? w1 : w2);
      out = (m == 0) ? o0 : ((m == 1) ? o1 : o2);
    }
    f4 v = reinterpret_cast<const f4*>(in)[j];
    u32x2 o = {pack2bf(v.x, v.y), pack2bf(v.z, v.w)};
    reinterpret_cast<u32x2*>(out)[j] = o;
  }
}

// ---------------- fused QKV projection GEMM ----------------
// 3-buffer LDS pipeline, prefetch depth 2, raw s_barrier + counted vmcnt
// (never 0 in steady state) -> staging latency spans ~1.5 iterations.
__global__ __launch_bounds__(256) void qkv_gemm(
    const unsigned short* __restrict__ Ab,
    const unsigned short* __restrict__ Wqb,
    const unsigned short* __restrict__ Wkb,
    const unsigned short* __restrict__ Wvb,
    const float* __restrict__ bqp, const float* __restrict__ bkp, const float* __restrict__ bvp,
    unsigned short* __restrict__ Qw, unsigned short* __restrict__ Kw, unsigned short* __restrict__ Vw) {
  __shared__ unsigned short smem[3][2][128 * 32];   // [buf][A/B]; epilogue aliases first 32KB

  int phys = blockIdx.x;
  int logical = (phys & 7) * 144 + (phys >> 3);
  int bn = logical % 18, bm = logical / 18;
  int mat = bn / 6, bnn = bn % 6;
  const unsigned short* Wm = (mat == 0) ? Wqb : ((mat == 1) ? Wkb : Wvb);
  const float* bias = (mat == 0) ? bqp : ((mat == 1) ? bkp : bvp);
  unsigned short* dst = (mat == 0) ? Qw : ((mat == 1) ? Kw : Vw);

  int t = threadIdx.x;
  int w = t >> 6, l = t & 63;
  int lg = l >> 4, ln = l & 15;
  int wm = w & 1, wn = w >> 1;

  int srow = t >> 2;             // staging row 0..63 (+64 for is=1)
  int sc8 = (t & 3) * 8;         // staging k-offset

  f32x4 acc[4][4];
#pragma unroll
  for (int i = 0; i < 4; i++)
#pragma unroll
    for (int j = 0; j < 4; j++) acc[i][j] = f32x4{0.f, 0.f, 0.f, 0.f};

  // ---- staging: 4 loads/thread/tile (A,B interleaved x2)
  auto stage = [&](int kt, int buf) {
#pragma unroll
    for (int is = 0; is < 2; ++is) {
      int chunk = is * 256 + t;
      int row = (is << 6) + srow;
      gload16(Ab + ((size_t)(bm * 128 + row)) * 768 + kt * 32 + sc8, &smem[buf][0][chunk * 8]);
      gload16(Wm + ((size_t)(bnn * 128 + row)) * 768 + kt * 32 + sc8, &smem[buf][1][chunk * 8]);
    }
  };

  // prologue: T0, T1 in flight; wait T0 only
  stage(0, 0);
  stage(1, 1);
  asm volatile("s_waitcnt vmcnt(4)" ::: "memory");
  __builtin_amdgcn_s_barrier();
  __builtin_amdgcn_sched_barrier(0);

  int buf = 0;
  for (int kt = 0; kt < 24; ++kt) {
    // issue T_{kt+2} first (longest possible flight time)
    if (kt < 22) {
      int nb = buf + 2; nb = (nb >= 3) ? nb - 3 : nb;
      stage(kt + 2, nb);
    }
    // compute on buf
    bf16x8 af[4], bfr[4];
#pragma unroll
    for (int i = 0; i < 4; i++) {
      af[i]  = *reinterpret_cast<const bf16x8*>(&smem[buf][0][(wm * 64 + i * 16 + ln) * 32 + lg * 8]);
      bfr[i] = *reinterpret_cast<const bf16x8*>(&smem[buf][1][(wn * 64 + i * 16 + ln) * 32 + lg * 8]);
    }
#pragma unroll
    for (int i = 0; i < 4; i++)
#pragma unroll
      for (int j = 0; j < 4; j++)
        acc[i][j] = __builtin_amdgcn_mfma_f32_16x16x32_bf16(af[i], bfr[j], acc[i][j], 0, 0, 0);

    if (kt < 23) {
      if (kt < 22) asm volatile("s_waitcnt vmcnt(4)" ::: "memory");  // T_{kt+1} landed, T_{kt+2} in flight
      else         asm volatile("s_waitcnt vmcnt(0)" ::: "memory");  // drain T_23
      __builtin_amdgcn_s_barrier();
      __builtin_amdgcn_sched_barrier(0);
    }
    buf = (buf == 2) ? 0 : buf + 1;
  }

  // epilogue: bias (+ Q scale), bf16, bounce through swizzled 128x128 LDS tile
  __syncthreads();
  unsigned short* ep = &smem[0][0][0];   // 128 rows x 128 cols, granule-16B ^ (row&15)
#pragma unroll
  for (int j = 0; j < 4; j++) {
    int col = wn * 64 + j * 16 + ln;
    float bv_ = bias[bnn * 128 + col];
#pragma unroll
    for (int i = 0; i < 4; i++) {
#pragma unroll
      for (int r = 0; r < 4; r++) {
        int row = wm * 64 + i * 16 + lg * 4 + r;
        float v = acc[i][j][r] + bv_;
        if (mat == 0) v *= 0.1803368801111244f;  // 0.125 * log2(e)
        int g = col >> 3;
        ep[row * 128 + (((g ^ (row & 15)) << 3) | (col & 7))] = f2bf(v);
      }
    }
  }
  __syncthreads();
  {
    int row = t >> 1, half = t & 1;
    int tok = bm * 128 + row;
    int bb = tok >> 12, ss = tok & 4095;
    int head = bnn * 2 + half;
    unsigned short* drow = dst + (((size_t)bb * 12 + head) * 4096 + ss) * 64;
#pragma unroll
    for (int kk8 = 0; kk8 < 8; ++kk8) {
      int g = (half * 8 + kk8) ^ (row & 15);
      *reinterpret_cast<u16x8*>(drow + kk8 * 8) =
          *reinterpret_cast<const u16x8*>(ep + row * 128 + g * 8);
    }
  }
}

// ---------------- fused band + global attention (frozen this round) ----------------
__global__ __launch_bounds__(512) void attn_kernel(
    const unsigned short* __restrict__ Qw,
    const unsigned short* __restrict__ Kw,
    const unsigned short* __restrict__ Vw,
    const int* __restrict__ amask,
    float* __restrict__ out) {
  __shared__ unsigned short Ks[2][64 * 64];   // [key][d], XOR-swizzled 8-elem granules
  __shared__ unsigned short Vt[2][64 * 64];   // [d][key], XOR-swizzled 4-elem granules
  __shared__ unsigned Msk[128];               // 4096-bit suppression mask

  int phys = blockIdx.x;
  int logical = (phys & 7) * 96 + (phys >> 3);  // XCD-contiguous heads
  int qc = logical & 31;
  int bh = logical >> 5;
  int b = bh / 12;
  int hh = bh % 12;
  int qbase = qc * 128;

  int t = threadIdx.x, w = t >> 6, l = t & 63;
  int lg = l >> 4, ln = l & 15;

  const unsigned short* Qbh = Qw + (size_t)bh * (NS * 64);
  const unsigned short* Kbh = Kw + (size_t)bh * (NS * 64);
  const unsigned short* Vbh = Vw + (size_t)bh * (NS * 64);
  const int* mrow = amask + b * NS;

#pragma unroll
  for (int r8 = 0; r8 < 8; ++r8) {
    int wp = r8 * 8 + w;
    unsigned long long bal = __ballot(mrow[wp * 64 + l] != 0);
    if (l == 0) {
      Msk[wp * 2] = (unsigned)bal;
      Msk[wp * 2 + 1] = (unsigned)(bal >> 32);
    }
  }

  int q = qbase + w * 16 + ln;   // this lane's q column
  int qwmin = qbase + w * 16;

  bf16x8 qf[2];
  {
    const unsigned short* qp = Qbh + (size_t)q * 64 + lg * 8;
    qf[0] = *reinterpret_cast<const bf16x8*>(qp);
    qf[1] = *reinterpret_cast<const bf16x8*>(qp + 32);
  }

  float m_s = -1e30f, l_s = 0.f;   // l_s: per-lane partial, reduced at the end
  f32x4 oacc[4];
#pragma unroll
  for (int i = 0; i < 4; i++) oacc[i] = f32x4{0.f, 0.f, 0.f, 0.f};

  int tt_lo = (qbase >= 256) ? 0 : ((256 - qbase) >> 6);
  int tt_hi_raw = (NS + 192 - qbase) >> 6;
  int tt_hi = tt_hi_raw < 9 ? tt_hi_raw : 9;
  int ntl = tt_hi - tt_lo + 2;

  int krow = t >> 3, gran = t & 7;          // K staging coords
  int p2 = t & 31, d0v = (t >> 5) * 4;      // V staging coords

  // prologue: stage tile 0 (global keys) into buffer 0
  {
    gload16(Kbh + (size_t)krow * 64 + (gran ^ (krow & 7)) * 8, &Ks[0][0] + t * 8);
    const unsigned short* vp0 = Vbh + (size_t)(2 * p2) * 64 + d0v;
    u16x4 va = *reinterpret_cast<const u16x4*>(vp0);
    u16x4 vb = *reinterpret_cast<const u16x4*>(vp0 + 64);
#pragma unroll
    for (int j = 0; j < 4; ++j) {
      int d = d0v + j;
      unsigned val = (unsigned)va[j] | ((unsigned)vb[j] << 16);
      *reinterpret_cast<unsigned*>(&Vt[0][0] + d * 64 + ((2 * p2) ^ ((d & 15) << 2))) = val;
    }
  }
  __syncthreads();

  for (int idx = 0; idx < ntl; ++idx) {
    int cur = idx & 1;
    int key0 = (idx == 0) ? 0 : (qbase - 256 + (tt_lo + idx - 1) * 64);
    bool has_next = (idx + 1) < ntl;

    // ---- issue next tile's loads (K -> LDS async, V -> regs) before compute
    u16x4 va, vb;
    if (has_next) {
      int nk0 = qbase - 256 + (tt_lo + idx) * 64;
      gload16(Kbh + (size_t)(nk0 + krow) * 64 + (gran ^ (krow & 7)) * 8,
              &Ks[cur ^ 1][0] + t * 8);
      const unsigned short* vp0 = Vbh + (size_t)(nk0 + 2 * p2) * 64 + d0v;
      va = *reinterpret_cast<const u16x4*>(vp0);
      vb = *reinterpret_cast<const u16x4*>(vp0 + 64);
    }

    // ---- per-wave tile relevance
    bool relevant = (idx == 0) ||
                    ((key0 + 63 >= qwmin - 256) && (key0 <= qwmin + 15 + 256));
    if (relevant) {
      // ---- S^T = K @ Q^T: sa[nt] reg r = S[key0+16nt+4lg+r][q]
      const unsigned short* ksb = &Ks[cur][0];
      f32x4 sa[4];
#pragma unroll
      for (int nt = 0; nt < 4; nt++) sa[nt] = f32x4{0.f, 0.f, 0.f, 0.f};
#pragma unroll
      for (int nt = 0; nt < 4; nt++) {
        int key = nt * 16 + ln;
#pragma unroll
        for (int ks = 0; ks < 2; ++ks) {
          int dby = (ks * 64 + lg * 16) ^ ((key & 7) << 4);
          bf16x8 kf = *reinterpret_cast<const bf16x8*>(ksb + key * 64 + (dby >> 1));
          sa[nt] = __builtin_amdgcn_mfma_f32_16x16x32_bf16(kf, qf[ks], sa[nt], 0, 0, 0);
        }
      }

      // ---- masking (band tiles; skipped on clean interior tiles)
      if (idx > 0) {
        unsigned mw0 = Msk[key0 >> 5], mw1 = Msk[(key0 >> 5) + 1];
        bool clean = ((mw0 | mw1) == 0) && (key0 >= qwmin - 241) && (key0 <= qwmin + 193);
        if (!clean) {
#pragma unroll
          for (int nt = 0; nt < 4; nt++) {
            unsigned mword = (nt & 2) ? mw1 : mw0;
#pragma unroll
            for (int r = 0; r < 4; r++) {
              int key = key0 + 16 * nt + 4 * lg + r;
              bool sup = (mword >> ((16 * (nt & 1) + 4 * lg + r) & 31)) & 1;
              bool bad = sup || ((unsigned)(key - q + NW) > 2u * NW);
              if (bad) sa[nt][r] = -1e30f;
            }
          }
        }
      }

      // ---- online softmax: in-lane max; shfl-reduce only on rescale trigger
      float tmax = sa[0][0];
#pragma unroll
      for (int nt = 0; nt < 4; nt++)
#pragma unroll
        for (int r = 0; r < 4; r++) tmax = fmaxf(tmax, sa[nt][r]);
      if (!__all(tmax - m_s <= 8.f)) {
        tmax = fmaxf(tmax, __shfl_xor(tmax, 16, 64));
        tmax = fmaxf(tmax, __shfl_xor(tmax, 32, 64));
        float mn = fmaxf(m_s, tmax);
        float scl = exp2_fast(m_s - mn);
        m_s = mn;
        l_s *= scl;
#pragma unroll
        for (int i = 0; i < 4; i++) oacc[i] *= scl;
      }
#pragma unroll
      for (int nt = 0; nt < 4; nt++)
#pragma unroll
        for (int r = 0; r < 4; r++) {
          float p = exp2_fast(sa[nt][r] - m_s);
          sa[nt][r] = p;
          l_s += p;
        }

      // ---- P -> bf16 (v_cvt_pk_bf16_f32), stays in registers
      union { bf16_t bb[8]; bf16x8 v; } pf0, pf1;
#pragma unroll
      for (int r = 0; r < 4; r++) {
        pf0.bb[r]     = (bf16_t)sa[0][r];
        pf0.bb[4 + r] = (bf16_t)sa[1][r];
        pf1.bb[r]     = (bf16_t)sa[2][r];
        pf1.bb[4 + r] = (bf16_t)sa[3][r];
      }

      // ---- PV: O^T += V^T @ P^T (A = V^T rows, granule-4 swizzle, conflict-free)
      const unsigned short* vtb = &Vt[cur][0];
#pragma unroll
      for (int ks = 0; ks < 2; ++ks) {
        bf16x8 pv = ks ? pf1.v : pf0.v;
#pragma unroll
        for (int nt = 0; nt < 4; ++nt) {
          int d = nt * 16 + ln;
          int sw = (d & 15) << 2;
          int e0 = (32 * ks + 4 * lg) ^ sw;
          int e1 = (32 * ks + 16 + 4 * lg) ^ sw;
          union { u16x4 h[2]; bf16x8 v; } vf;
          vf.h[0] = *reinterpret_cast<const u16x4*>(vtb + d * 64 + e0);
          vf.h[1] = *reinterpret_cast<const u16x4*>(vtb + d * 64 + e1);
          oacc[nt] = __builtin_amdgcn_mfma_f32_16x16x32_bf16(vf.v, pv, oacc[nt], 0, 0, 0);
        }
      }
    }

    // ---- land prefetched V into the other buffer
    if (has_next) {
      unsigned short* vtn = &Vt[cur ^ 1][0];
#pragma unroll
      for (int j = 0; j < 4; ++j) {
        int d = d0v + j;
        unsigned val = (unsigned)va[j] | ((unsigned)vb[j] << 16);
        *reinterpret_cast<unsigned*>(vtn + d * 64 + ((2 * p2) ^ ((d & 15) << 2))) = val;
      }
    }
    __syncthreads();
  }

  // ---- finalize: reduce partial l_s across the 4 lanes sharing this q
  l_s += __shfl_xor(l_s, 16, 64);
  l_s += __shfl_xor(l_s, 32, 64);
  float inv = 1.0f / l_s;
  float* orow = out + ((size_t)q * NB + b) * ND + hh * 64;
#pragma unroll
  for (int nt = 0; nt < 4; nt++) {
    f4 o;
#pragma unroll
    for (int r = 0; r < 4; r++) o[r] = oacc[nt][r] * inv;
    *reinterpret_cast<f4*>(orow + nt * 16 + 4 * lg) = o;
  }
}

extern "C" void kernel_launch(void* const* d_in, const int* in_sizes, int n_in,
                              void* d_out, int out_size, void* d_ws, size_t ws_size,
                              hipStream_t stream) {
  (void)in_sizes; (void)n_in; (void)out_size; (void)ws_size;
  const float* hidden = (const float*)d_in[0];
  const int*   amask  = (const int*)d_in[1];
  const float* Wq = (const float*)d_in[2];
  const float* bq = (const float*)d_in[3];
  const float* Wk = (const float*)d_in[4];
  const float* bk = (const float*)d_in[5];
  const float* Wv = (const float*)d_in[6];
  const float* bv = (const float*)d_in[7];
  float* out = (float*)d_out;

  char* p = (char*)d_ws;
  unsigned short* hb  = (unsigned short*)p; p += (size_t)8192 * 768 * 2;
  unsigned short* wqb = (unsigned short*)p; p += (size_t)768 * 768 * 2;
  unsigned short* wkb = (unsigned short*)p; p += (size_t)768 * 768 * 2;
  unsigned short* wvb = (unsigned short*)p; p += (size_t)768 * 768 * 2;
  unsigned short* Qws = (unsigned short*)p; p += (size_t)24 * 4096 * 64 * 2;
  unsigned short* Kws = (unsigned short*)p; p += (size_t)24 * 4096 * 64 * 2;
  unsigned short* Vws = (unsigned short*)p; p += (size_t)24 * 4096 * 64 * 2;

  cast_all<<<2048, 256, 0, stream>>>(hidden, Wq, Wk, Wv, hb, wqb, wkb, wvb);
  qkv_gemm<<<64 * 18, 256, 0, stream>>>(hb, wqb, wkb, wvb, bq, bk, bv, Qws, Kws, Vws);
  attn_kernel<<<24 * 32, 512, 0, stream>>>(Qws, Kws, Vws, amask, out);
}